// Round 7
// baseline (2162.460 us; speedup 1.0000x reference)
//
#include <hip/hip_runtime.h>
#include <math.h>

// Traffic foundation model, round 6 (perf-only, bit-identical numerics vs r5):
// (1) XCD-chunked 1D grid swizzle on expert GEMMs: all sb-blocks of a weight
//     n-tile run consecutively on one XCD -> weight tile fetched once, L2-hot.
// (2) L0 u-pass writes h as split-2 planes (same f32 -> same bits); gemm2_dn
//     loads planes via global_load_lds directly (no f32 re-read / re-split).
// (3) tconv kernels: 64x64 tiles, 128B-coalesced writes (2x faster transposes).
// Precision map (validated r2-r5): proj split-3; QKV/Wo/L0-experts split-2
// (17-bit); router exact f32; attn f32 core; L1 experts plain bf16.

#define TTOK 4096
#define FDIM 3072
#define MAXSLOT 9216   // 8192 + 8*127 pad, 128-aligned offsets; 72 sb-blocks

typedef __attribute__((ext_vector_type(8))) short short8;
typedef __attribute__((ext_vector_type(4))) float f32x4;

__device__ __forceinline__ float bf2f(unsigned short u) {
  return __uint_as_float(((unsigned int)u) << 16);
}
__device__ __forceinline__ unsigned short f2bf(float f) {
  unsigned int u = __float_as_uint(f);
  u += 0x7fffu + ((u >> 16) & 1u);
  return (unsigned short)(u >> 16);
}
__device__ __forceinline__ void split3f(float a, unsigned short& h, unsigned short& m,
                                        unsigned short& l) {
  h = f2bf(a);
  float r = a - bf2f(h);
  m = f2bf(r);
  r -= bf2f(m);
  l = f2bf(r);
}
__device__ __forceinline__ void split2f(float a, unsigned short& h, unsigned short& m) {
  h = f2bf(a);
  m = f2bf(a - bf2f(h));
}
__device__ __forceinline__ void gload16(const void* g, void* l) {
  __builtin_amdgcn_global_load_lds((const __attribute__((address_space(1))) unsigned int*)g,
                                   (__attribute__((address_space(3))) unsigned int*)l, 16, 0, 0);
}

#define MFMA_TERM(ACC, PA, PB)                                                              \
  _Pragma("unroll") for (int i_ = 0; i_ < 4; ++i_)                                          \
      _Pragma("unroll") for (int j_ = 0; j_ < 4; ++j_)                                      \
          ACC[i_][j_] = __builtin_amdgcn_mfma_f32_16x16x32_bf16(af[PA][i_], bf[PB][j_],     \
                                                                ACC[i_][j_], 0, 0, 0);
#define MFMA_SPLIT3(ACC)  \
  MFMA_TERM(ACC, 0, 2) MFMA_TERM(ACC, 2, 0) MFMA_TERM(ACC, 1, 1) \
  MFMA_TERM(ACC, 0, 1) MFMA_TERM(ACC, 1, 0) MFMA_TERM(ACC, 0, 0)
#define MFMA_SPLIT2(ACC)  \
  MFMA_TERM(ACC, 0, 1) MFMA_TERM(ACC, 1, 0) MFMA_TERM(ACC, 0, 0)

// ---------------------------------------------------------------- small kernels

__global__ void rope_cache_k(float* __restrict__ cosb, float* __restrict__ sinb) {
  int s = blockIdx.x, i = threadIdx.x;                 // grid 1024 x 32
  float inv = powf(10000.0f, -(float)i / 32.0f);
  float a = (float)s * inv;
  cosb[s * 32 + i] = cosf(a);
  sinb[s * 32 + i] = sinf(a);
}

__global__ void build_ctx_k(const int* ts, const int* dow, const int* mon, const int* hol,
                            const int* loc, const int* road, const int* wth,
                            const float* te, const float* de, const float* me, const float* he,
                            const float* le, const float* re, const float* we,
                            float* __restrict__ ctx) {
  int b = blockIdx.x;
  int j = blockIdx.y * 256 + threadIdx.x;              // grid (4,6) x 256
  float v;
  if (j < 192)       v = te[ts[b] * 192 + j];
  else if (j < 384)  v = de[dow[b] * 192 + (j - 192)];
  else if (j < 576)  v = me[mon[b] * 192 + (j - 384)];
  else if (j < 768)  v = he[hol[b] * 192 + (j - 576)];
  else if (j < 1152) v = le[loc[b] * 384 + (j - 768)];
  else if (j < 1344) v = re[road[b] * 192 + (j - 1152)];
  else               v = we[wth[b] * 192 + (j - 1344)];
  ctx[b * 1536 + j] = v;
}

__global__ void build_bias_k(const float* __restrict__ ctx, const float* __restrict__ pw,
                             const float* __restrict__ pb, float* __restrict__ biasB) {
  int b = blockIdx.x;
  int d = blockIdx.y * 256 + threadIdx.x;              // grid (4,3) x 256
  float s = pb[d];
  const float* cb = ctx + b * 1536;
  for (int j = 0; j < 1536; ++j) s += cb[j] * pw[(size_t)(768 + j) * 768 + d];
  biasB[b * 768 + d] = s;
}

// ---- transpose kernels: 64x64 tiles, block (64,4), 128B-coalesced both sides ----

// split-3 (proj only): dst[p][n][k] = split(src[k][n])
__global__ void tconv3_k(const float* __restrict__ src, unsigned short* __restrict__ dst,
                         size_t dPS, int K, int N, size_t sstride, size_t dstride) {
  __shared__ float tile[64][65];
  src += (size_t)blockIdx.z * sstride;
  size_t dbase = (size_t)blockIdx.z * dstride;
  int n0 = blockIdx.x * 64, k0 = blockIdx.y * 64;
  int tx = threadIdx.x, ty = threadIdx.y;
  #pragma unroll
  for (int r = 0; r < 16; ++r)
    tile[ty + r * 4][tx] = src[(size_t)(k0 + ty + r * 4) * N + n0 + tx];
  __syncthreads();
  #pragma unroll
  for (int r = 0; r < 16; ++r) {
    int n = n0 + ty + r * 4;
    unsigned short h, m, lo;
    split3f(tile[tx][ty + r * 4], h, m, lo);
    size_t di = dbase + (size_t)n * K + k0 + tx;
    dst[di] = h; dst[di + dPS] = m; dst[di + 2 * dPS] = lo;
  }
}

// split-2: dst[p][n][k], 2 planes
__global__ void tconv2_k(const float* __restrict__ src, unsigned short* __restrict__ dst,
                         size_t dPS, int K, int N, size_t sstride, size_t dstride) {
  __shared__ float tile[64][65];
  src += (size_t)blockIdx.z * sstride;
  size_t dbase = (size_t)blockIdx.z * dstride;
  int n0 = blockIdx.x * 64, k0 = blockIdx.y * 64;
  int tx = threadIdx.x, ty = threadIdx.y;
  #pragma unroll
  for (int r = 0; r < 16; ++r)
    tile[ty + r * 4][tx] = src[(size_t)(k0 + ty + r * 4) * N + n0 + tx];
  __syncthreads();
  #pragma unroll
  for (int r = 0; r < 16; ++r) {
    int n = n0 + ty + r * 4;
    unsigned short h, m;
    split2f(tile[tx][ty + r * 4], h, m);
    size_t di = dbase + (size_t)n * K + k0 + tx;
    dst[di] = h; dst[di + dPS] = m;
  }
}

// single plane (plain bf16, L1 experts)
__global__ void tconv_k(const float* __restrict__ src, unsigned short* __restrict__ dst,
                        int K, int N, size_t sstride, size_t dstride) {
  __shared__ float tile[64][65];
  src += (size_t)blockIdx.z * sstride;
  unsigned short* d = dst + (size_t)blockIdx.z * dstride;
  int n0 = blockIdx.x * 64, k0 = blockIdx.y * 64;
  int tx = threadIdx.x, ty = threadIdx.y;
  #pragma unroll
  for (int r = 0; r < 16; ++r)
    tile[ty + r * 4][tx] = src[(size_t)(k0 + ty + r * 4) * N + n0 + tx];
  __syncthreads();
  #pragma unroll
  for (int r = 0; r < 16; ++r) {
    int n = n0 + ty + r * 4;
    d[(size_t)n * K + k0 + tx] = f2bf(tile[tx][ty + r * 4]);
  }
}

// gather word_emb rows -> 3 planes. grid 4096 x 192
__global__ void gconv3_k(const float* __restrict__ we, const int* __restrict__ ids,
                         unsigned short* __restrict__ x3, size_t pPS) {
  int t = blockIdx.x;
  int d = threadIdx.x << 2;
  float4 v = *(const float4*)(we + (size_t)ids[t] * 768 + d);
  ushort4 vh, vm, vl;
  split3f(v.x, vh.x, vm.x, vl.x);
  split3f(v.y, vh.y, vm.y, vl.y);
  split3f(v.z, vh.z, vm.z, vl.z);
  split3f(v.w, vh.w, vm.w, vl.w);
  size_t o = (size_t)t * 768 + d;
  *(ushort4*)(x3 + o) = vh;
  *(ushort4*)(x3 + pPS + o) = vm;
  *(ushort4*)(x3 + 2 * pPS + o) = vl;
}

// OUT: 0 f32 only; 1 2-plane only; 2 f32 + 2-plane; 3 f32 + single-bf16(plane0)
template <int OUT>
__global__ __launch_bounds__(256) void rmsnorm_k(const float* __restrict__ xin,
                                                 const float* __restrict__ w,
                                                 float* __restrict__ yf,
                                                 unsigned short* __restrict__ yb, size_t pPS) {
  int t = blockIdx.x;
  int tid = threadIdx.x;
  const float* xr = xin + (size_t)t * 768;
  float v0 = xr[tid], v1 = xr[tid + 256], v2 = xr[tid + 512];
  float ss = v0 * v0 + v1 * v1 + v2 * v2;
  #pragma unroll
  for (int o = 32; o > 0; o >>= 1) ss += __shfl_xor(ss, o);
  __shared__ float wss[4];
  if ((tid & 63) == 0) wss[tid >> 6] = ss;
  __syncthreads();
  float tot = wss[0] + wss[1] + wss[2] + wss[3];
  float inv = 1.0f / sqrtf(tot / 768.0f + 1e-6f);
  float o0 = v0 * inv * w[tid], o1 = v1 * inv * w[tid + 256], o2 = v2 * inv * w[tid + 512];
  if (OUT != 1) {
    float* yr = yf + (size_t)t * 768;
    yr[tid] = o0; yr[tid + 256] = o1; yr[tid + 512] = o2;
  }
  if (OUT == 1 || OUT == 2) {
    unsigned short* yr = yb + (size_t)t * 768;
    unsigned short h, m;
    split2f(o0, h, m); yr[tid] = h;       yr[tid + pPS] = m;
    split2f(o1, h, m); yr[tid + 256] = h; yr[tid + 256 + pPS] = m;
    split2f(o2, h, m); yr[tid + 512] = h; yr[tid + 512 + pPS] = m;
  }
  if (OUT == 3) {
    unsigned short* yr = yb + (size_t)t * 768;
    yr[tid] = f2bf(o0); yr[tid + 256] = f2bf(o1); yr[tid + 512] = f2bf(o2);
  }
}

// rope in-place on f32 qkv [T][2304] (q at 0, k at 768)
__global__ __launch_bounds__(256) void rope_apply_k(float* __restrict__ qkv,
                                                    const float* __restrict__ cosb,
                                                    const float* __restrict__ sinb) {
  int idx = blockIdx.x * 256 + threadIdx.x;            // grid 6144
  int j = idx & 31;
  int hh = (idx >> 5) % 12;
  int t = idx / 384;
  int s = t & 1023;
  float c = cosb[s * 32 + j], sn = sinb[s * 32 + j];
  size_t base = (size_t)t * 2304 + hh * 64 + j;
  float q1 = qkv[base], q2 = qkv[base + 32];
  qkv[base]      = q1 * c - q2 * sn;
  qkv[base + 32] = q2 * c + q1 * sn;
  size_t kb = base + 768;
  float k1 = qkv[kb], k2 = qkv[kb + 32];
  qkv[kb]      = k1 * c - k2 * sn;
  qkv[kb + 32] = k2 * c + k1 * sn;
}

// ---------------------------------------------------------------- split-3 dense GEMM (proj only)
template <int EPI>
__global__ __launch_bounds__(256) void gemm3(const unsigned short* __restrict__ A, size_t aPS,
                                             const unsigned short* __restrict__ BT, size_t bPS,
                                             float* __restrict__ Cf, int N, int K,
                                             const float* __restrict__ rowBias) {
  __shared__ __align__(16) unsigned short As[3][4096];
  __shared__ __align__(16) unsigned short Bs[3][4096];
  int tid = threadIdx.x, w = tid >> 6, l = tid & 63, lr = l & 15, lg = l >> 4;
  int m0 = blockIdx.y * 128, n0 = blockIdx.x * 128;
  size_t aoff = (size_t)(m0 + 32 * w + lr) * K + lg * 8;
  size_t boff = (size_t)(n0 + 32 * w + lr) * K + lg * 8;
  size_t aoff1 = aoff + (size_t)16 * K, boff1 = boff + (size_t)16 * K;
  f32x4 acc[4][4];
  #pragma unroll
  for (int i = 0; i < 4; ++i)
    #pragma unroll
    for (int j = 0; j < 4; ++j) acc[i][j] = (f32x4){0.f, 0.f, 0.f, 0.f};
  int wr = w >> 1, wc = w & 1;
  for (int k0 = 0; k0 < K; k0 += 32) {
    #pragma unroll
    for (int p = 0; p < 3; ++p) {
      gload16(A + p * aPS + aoff + k0,  &As[p][1024 * w]);
      gload16(A + p * aPS + aoff1 + k0, &As[p][1024 * w + 512]);
      gload16(BT + p * bPS + boff + k0,  &Bs[p][1024 * w]);
      gload16(BT + p * bPS + boff1 + k0, &Bs[p][1024 * w + 512]);
    }
    __syncthreads();
    short8 af[3][4], bf[3][4];
    #pragma unroll
    for (int p = 0; p < 3; ++p)
      #pragma unroll
      for (int i = 0; i < 4; ++i) {
        af[p][i] = *(const short8*)(&As[p][(wr * 4 + i) * 512 + l * 8]);
        bf[p][i] = *(const short8*)(&Bs[p][(wc * 4 + i) * 512 + l * 8]);
      }
    MFMA_SPLIT3(acc)
    __syncthreads();
  }
  int colb = n0 + wc * 64 + lr;
  int rowb = m0 + wr * 64 + lg * 4;
  #pragma unroll
  for (int i = 0; i < 4; ++i)
    #pragma unroll
    for (int j = 0; j < 4; ++j) {
      int col = colb + j * 16;
      #pragma unroll
      for (int r = 0; r < 4; ++r) {
        int row = rowb + i * 16 + r;
        size_t idx = (size_t)row * N + col;
        float v = acc[i][j][r];
        if (EPI == 0)      Cf[idx] = v;
        else if (EPI == 2) Cf[idx] += v;
        else               Cf[idx] = v + rowBias[(row >> 10) * 768 + col];
      }
    }
}

// ---------------------------------------------------------------- split-2 dense GEMM (QKV, Wo)
template <int EPI>  // 0: f32 store; 2: f32 +=
__global__ __launch_bounds__(256) void gemm2(const unsigned short* __restrict__ A, size_t aPS,
                                             const unsigned short* __restrict__ BT, size_t bPS,
                                             float* __restrict__ Cf, int N, int K) {
  __shared__ __align__(16) unsigned short As[2][4096];
  __shared__ __align__(16) unsigned short Bs[2][4096];
  int tid = threadIdx.x, w = tid >> 6, l = tid & 63, lr = l & 15, lg = l >> 4;
  int m0 = blockIdx.y * 128, n0 = blockIdx.x * 128;
  size_t aoff = (size_t)(m0 + 32 * w + lr) * K + lg * 8;
  size_t boff = (size_t)(n0 + 32 * w + lr) * K + lg * 8;
  size_t aoff1 = aoff + (size_t)16 * K, boff1 = boff + (size_t)16 * K;
  f32x4 acc[4][4];
  #pragma unroll
  for (int i = 0; i < 4; ++i)
    #pragma unroll
    for (int j = 0; j < 4; ++j) acc[i][j] = (f32x4){0.f, 0.f, 0.f, 0.f};
  int wr = w >> 1, wc = w & 1;
  for (int k0 = 0; k0 < K; k0 += 32) {
    #pragma unroll
    for (int p = 0; p < 2; ++p) {
      gload16(A + p * aPS + aoff + k0,  &As[p][1024 * w]);
      gload16(A + p * aPS + aoff1 + k0, &As[p][1024 * w + 512]);
      gload16(BT + p * bPS + boff + k0,  &Bs[p][1024 * w]);
      gload16(BT + p * bPS + boff1 + k0, &Bs[p][1024 * w + 512]);
    }
    __syncthreads();
    short8 af[2][4], bf[2][4];
    #pragma unroll
    for (int p = 0; p < 2; ++p)
      #pragma unroll
      for (int i = 0; i < 4; ++i) {
        af[p][i] = *(const short8*)(&As[p][(wr * 4 + i) * 512 + l * 8]);
        bf[p][i] = *(const short8*)(&Bs[p][(wc * 4 + i) * 512 + l * 8]);
      }
    MFMA_SPLIT2(acc)
    __syncthreads();
  }
  int colb = n0 + wc * 64 + lr;
  int rowb = m0 + wr * 64 + lg * 4;
  #pragma unroll
  for (int i = 0; i < 4; ++i)
    #pragma unroll
    for (int j = 0; j < 4; ++j) {
      int col = colb + j * 16;
      #pragma unroll
      for (int r = 0; r < 4; ++r) {
        int row = rowb + i * 16 + r;
        size_t idx = (size_t)row * N + col;
        float v = acc[i][j][r];
        if (EPI == 0) Cf[idx] = v;
        else          Cf[idx] += v;
      }
    }
}

// ---------------------------------------------------------------- L0 experts (split-2)
// XCD-chunked 1D grid: nwg=1728 (72 sb x 24 n), L=(bid&7)*216+(bid>>3),
// col-major decode -> all sb-blocks of a weight n-tile consecutive on one XCD.
// FUSE 0: g-pass, store f32 gtmp. FUSE 1: u-pass, h=silu(g)*u -> split-2 planes.
template <int FUSE>
__global__ __launch_bounds__(256) void gemm2_gu(const unsigned short* __restrict__ X3, size_t xPS,
    const unsigned short* __restrict__ W2, size_t wPS, float* __restrict__ gout,
    unsigned short* __restrict__ hout, size_t hPS, const float* __restrict__ gin,
    const int* __restrict__ slot_token, const int* __restrict__ offs,
    const unsigned short* __restrict__ zp) {
  __shared__ __align__(16) unsigned short As[2][4096];
  __shared__ __align__(16) unsigned short Bs[2][4096];
  int L = ((blockIdx.x & 7) * 216) + (blockIdx.x >> 3);
  int sb = (L % 72) * 128;
  int n0 = (L / 72) * 128;
  if (sb >= offs[8]) return;
  int e = 0;
  #pragma unroll
  for (int i = 1; i < 8; ++i) if (sb >= offs[i]) e = i;
  int tid = threadIdx.x, w = tid >> 6, l = tid & 63, lr = l & 15, lg = l >> 4;
  const unsigned short* WE = W2 + (size_t)e * FDIM * 768;
  int t0 = slot_token[sb + 32 * w + lr];
  int t1 = slot_token[sb + 32 * w + 16 + lr];
  const unsigned short* a0[2];
  const unsigned short* a1[2];
  #pragma unroll
  for (int p = 0; p < 2; ++p) {
    a0[p] = (t0 < 0 ? zp : X3 + p * xPS + (size_t)t0 * 768) + lg * 8;
    a1[p] = (t1 < 0 ? zp : X3 + p * xPS + (size_t)t1 * 768) + lg * 8;
  }
  size_t boff = (size_t)(n0 + 32 * w + lr) * 768 + lg * 8;
  size_t boff1 = boff + (size_t)16 * 768;
  f32x4 acc[4][4];
  #pragma unroll
  for (int i = 0; i < 4; ++i)
    #pragma unroll
    for (int j = 0; j < 4; ++j) acc[i][j] = (f32x4){0.f, 0.f, 0.f, 0.f};
  int wr = w >> 1, wc = w & 1;
  for (int k0 = 0; k0 < 768; k0 += 32) {
    #pragma unroll
    for (int p = 0; p < 2; ++p) {
      gload16(a0[p] + k0, &As[p][1024 * w]);
      gload16(a1[p] + k0, &As[p][1024 * w + 512]);
      gload16(WE + p * wPS + boff + k0,  &Bs[p][1024 * w]);
      gload16(WE + p * wPS + boff1 + k0, &Bs[p][1024 * w + 512]);
    }
    __syncthreads();
    short8 af[2][4], bf[2][4];
    #pragma unroll
    for (int p = 0; p < 2; ++p)
      #pragma unroll
      for (int i = 0; i < 4; ++i) {
        af[p][i] = *(const short8*)(&As[p][(wr * 4 + i) * 512 + l * 8]);
        bf[p][i] = *(const short8*)(&Bs[p][(wc * 4 + i) * 512 + l * 8]);
      }
    MFMA_SPLIT2(acc)
    __syncthreads();
  }
  int colb = n0 + wc * 64 + lr;
  int rowb = sb + wr * 64 + lg * 4;
  #pragma unroll
  for (int i = 0; i < 4; ++i)
    #pragma unroll
    for (int j = 0; j < 4; ++j) {
      int col = colb + j * 16;
      #pragma unroll
      for (int r = 0; r < 4; ++r) {
        size_t idx = (size_t)(rowb + i * 16 + r) * FDIM + col;
        float v = acc[i][j][r];
        if (FUSE == 0) gout[idx] = v;
        else {
          float g = gin[idx];
          float h = g / (1.0f + expf(-g)) * v;         // silu(g)*u
          unsigned short hh, hm;
          split2f(h, hh, hm);
          hout[idx] = hh; hout[idx + hPS] = hm;
        }
      }
    }
}

// L0 down: A = h split-2 planes (direct gload16), B = wd 2 planes. N=768, K=3072.
// XCD-chunked 1D grid: nwg=432 (72 sb x 6 n), L=(bid&7)*54+(bid>>3).
__global__ __launch_bounds__(256) void gemm2_dn(const unsigned short* __restrict__ hpl, size_t hPS,
    const unsigned short* __restrict__ W2, size_t wPS, float* __restrict__ ob,
    const int* __restrict__ offs) {
  __shared__ __align__(16) unsigned short As[2][4096];
  __shared__ __align__(16) unsigned short Bs[2][4096];
  int L = ((blockIdx.x & 7) * 54) + (blockIdx.x >> 3);
  int sb = (L % 72) * 128;
  int n0 = (L / 72) * 128;
  if (sb >= offs[8]) return;
  int e = 0;
  #pragma unroll
  for (int i = 1; i < 8; ++i) if (sb >= offs[i]) e = i;
  int tid = threadIdx.x, w = tid >> 6, l = tid & 63, lr = l & 15, lg = l >> 4;
  const unsigned short* WE = W2 + (size_t)e * 768 * FDIM;
  size_t aoff = (size_t)(sb + 32 * w + lr) * FDIM + lg * 8;
  size_t aoff1 = aoff + (size_t)16 * FDIM;
  size_t boff = (size_t)(n0 + 32 * w + lr) * FDIM + lg * 8;
  size_t boff1 = boff + (size_t)16 * FDIM;
  f32x4 acc[4][4];
  #pragma unroll
  for (int i = 0; i < 4; ++i)
    #pragma unroll
    for (int j = 0; j < 4; ++j) acc[i][j] = (f32x4){0.f, 0.f, 0.f, 0.f};
  int wr = w >> 1, wc = w & 1;
  for (int k0 = 0; k0 < FDIM; k0 += 32) {
    #pragma unroll
    for (int p = 0; p < 2; ++p) {
      gload16(hpl + p * hPS + aoff + k0,  &As[p][1024 * w]);
      gload16(hpl + p * hPS + aoff1 + k0, &As[p][1024 * w + 512]);
      gload16(WE + p * wPS + boff + k0,  &Bs[p][1024 * w]);
      gload16(WE + p * wPS + boff1 + k0, &Bs[p][1024 * w + 512]);
    }
    __syncthreads();
    short8 af[2][4], bf[2][4];
    #pragma unroll
    for (int p = 0; p < 2; ++p)
      #pragma unroll
      for (int i = 0; i < 4; ++i) {
        af[p][i] = *(const short8*)(&As[p][(wr * 4 + i) * 512 + l * 8]);
        bf[p][i] = *(const short8*)(&Bs[p][(wc * 4 + i) * 512 + l * 8]);
      }
    MFMA_SPLIT2(acc)
    __syncthreads();
  }
  int colb = n0 + wc * 64 + lr;
  int rowb = sb + wr * 64 + lg * 4;
  #pragma unroll
  for (int i = 0; i < 4; ++i)
    #pragma unroll
    for (int j = 0; j < 4; ++j) {
      int col = colb + j * 16;
      #pragma unroll
      for (int r = 0; r < 4; ++r)
        ob[(size_t)(rowb + i * 16 + r) * 768 + col] = acc[i][j][r];
    }
}

// ---------------------------------------------------------------- L1 experts (plain bf16)
// N-concat gate+up, XCD-chunked 1D grid: nwg=3456 (72 sb x 48 n), L=(bid&7)*432+(bid>>3).
__global__ __launch_bounds__(256) void gemm_gu2(const unsigned short* __restrict__ xnb,
    const unsigned short* __restrict__ wgT, const unsigned short* __restrict__ wuT,
    unsigned short* __restrict__ gub, const int* __restrict__ slot_token,
    const int* __restrict__ offs, const unsigned short* __restrict__ zp) {
  __shared__ __align__(16) unsigned short As[4096], Bs[4096];
  int L = ((blockIdx.x & 7) * 432) + (blockIdx.x >> 3);
  int sb = (L % 72) * 128;
  int n0 = (L / 72) * 128;
  if (sb >= offs[8]) return;
  int e = 0;
  #pragma unroll
  for (int i = 1; i < 8; ++i) if (sb >= offs[i]) e = i;
  int tid = threadIdx.x, w = tid >> 6, l = tid & 63, lr = l & 15, lg = l >> 4;
  int nl = (n0 < FDIM) ? n0 : (n0 - FDIM);
  const unsigned short* WE = ((n0 < FDIM) ? wgT : wuT) + (size_t)e * FDIM * 768;
  unsigned short* OB = (n0 < FDIM) ? gub : (gub + (size_t)MAXSLOT * FDIM);
  int t0 = slot_token[sb + 32 * w + lr];
  int t1 = slot_token[sb + 32 * w + 16 + lr];
  const unsigned short* ga0 = (t0 < 0 ? zp : xnb + (size_t)t0 * 768) + lg * 8;
  const unsigned short* ga1 = (t1 < 0 ? zp : xnb + (size_t)t1 * 768) + lg * 8;
  const unsigned short* gb0 = WE + (size_t)(nl + 32 * w + lr) * 768 + lg * 8;
  const unsigned short* gb1 = gb0 + 16 * 768;
  f32x4 acc[4][4];
  #pragma unroll
  for (int i = 0; i < 4; ++i)
    #pragma unroll
    for (int j = 0; j < 4; ++j) acc[i][j] = (f32x4){0.f, 0.f, 0.f, 0.f};
  int wr = w >> 1, wc = w & 1;
  for (int k0 = 0; k0 < 768; k0 += 32) {
    gload16(ga0 + k0, As + 1024 * w);
    gload16(ga1 + k0, As + 1024 * w + 512);
    gload16(gb0 + k0, Bs + 1024 * w);
    gload16(gb1 + k0, Bs + 1024 * w + 512);
    __syncthreads();
    short8 af[4], bf[4];
    #pragma unroll
    for (int i = 0; i < 4; ++i) af[i] = *(const short8*)(As + (wr * 4 + i) * 512 + l * 8);
    #pragma unroll
    for (int j = 0; j < 4; ++j) bf[j] = *(const short8*)(Bs + (wc * 4 + j) * 512 + l * 8);
    #pragma unroll
    for (int i = 0; i < 4; ++i)
      #pragma unroll
      for (int j = 0; j < 4; ++j)
        acc[i][j] = __builtin_amdgcn_mfma_f32_16x16x32_bf16(af[i], bf[j], acc[i][j], 0, 0, 0);
    __syncthreads();
  }
  int colb = nl + wc * 64 + lr;
  int rowb = sb + wr * 64 + lg * 4;
  #pragma unroll
  for (int i = 0; i < 4; ++i)
    #pragma unroll
    for (int j = 0; j < 4; ++j) {
      int col = colb + j * 16;
      #pragma unroll
      for (int r = 0; r < 4; ++r)
        OB[(size_t)(rowb + i * 16 + r) * FDIM + col] = f2bf(acc[i][j][r]);
    }
}

// h = silu(g) * u, bf16 in/out. grid 13824 x 256 (8 elems/thread over MAXSLOT*FDIM)
__global__ void silu_mul_k(const unsigned short* __restrict__ gub,
                           unsigned short* __restrict__ hb) {
  size_t i = ((size_t)blockIdx.x * 256 + threadIdx.x) * 8;
  const unsigned short* u = gub + (size_t)MAXSLOT * FDIM;
  ushort4 g0 = *(const ushort4*)(gub + i);
  ushort4 g1 = *(const ushort4*)(gub + i + 4);
  ushort4 u0 = *(const ushort4*)(u + i);
  ushort4 u1 = *(const ushort4*)(u + i + 4);
  float gf[8] = {bf2f(g0.x), bf2f(g0.y), bf2f(g0.z), bf2f(g0.w),
                 bf2f(g1.x), bf2f(g1.y), bf2f(g1.z), bf2f(g1.w)};
  float uf[8] = {bf2f(u0.x), bf2f(u0.y), bf2f(u0.z), bf2f(u0.w),
                 bf2f(u1.x), bf2f(u1.y), bf2f(u1.z), bf2f(u1.w)};
  ushort4 h0, h1;
  h0.x = f2bf(gf[0] / (1.0f + expf(-gf[0])) * uf[0]);
  h0.y = f2bf(gf[1] / (1.0f + expf(-gf[1])) * uf[1]);
  h0.z = f2bf(gf[2] / (1.0f + expf(-gf[2])) * uf[2]);
  h0.w = f2bf(gf[3] / (1.0f + expf(-gf[3])) * uf[3]);
  h1.x = f2bf(gf[4] / (1.0f + expf(-gf[4])) * uf[4]);
  h1.y = f2bf(gf[5] / (1.0f + expf(-gf[5])) * uf[5]);
  h1.z = f2bf(gf[6] / (1.0f + expf(-gf[6])) * uf[6]);
  h1.w = f2bf(gf[7] / (1.0f + expf(-gf[7])) * uf[7]);
  *(ushort4*)(hb + i) = h0;
  *(ushort4*)(hb + i + 4) = h1;
}

// L1 down (plain bf16), XCD-chunked 1D grid: nwg=432, L=(bid&7)*54+(bid>>3).
__global__ __launch_bounds__(256) void gemm_d(const unsigned short* __restrict__ hb,
    const unsigned short* __restrict__ wdT, unsigned short* __restrict__ ob,
    const int* __restrict__ offs) {
  __shared__ __align__(16) unsigned short As[4096], Bs[4096];
  int L = ((blockIdx.x & 7) * 54) + (blockIdx.x >> 3);
  int sb = (L % 72) * 128;
  int n0 = (L / 72) * 128;
  if (sb >= offs[8]) return;
  int e = 0;
  #pragma unroll
  for (int i = 1; i < 8; ++i) if (sb >= offs[i]) e = i;
  int tid = threadIdx.x, w = tid >> 6, l = tid & 63, lr = l & 15, lg = l >> 4;
  const unsigned short* ga0 = hb + (size_t)(sb + 32 * w + lr) * FDIM + lg * 8;
  const unsigned short* ga1 = ga0 + (size_t)16 * FDIM;
  const unsigned short* WdE = wdT + (size_t)e * 768 * FDIM;
  const unsigned short* gb0 = WdE + (size_t)(n0 + 32 * w + lr) * FDIM + lg * 8;
  const unsigned short* gb1 = gb0 + (size_t)16 * FDIM;
  f32x4 acc[4][4];
  #pragma unroll
  for (int i = 0; i < 4; ++i)
    #pragma unroll
    for (int j = 0; j < 4; ++j) acc[i][j] = (f32x4){0.f, 0.f, 0.f, 0.f};
  int wr = w >> 1, wc = w & 1;
  for (int k0 = 0; k0 < FDIM; k0 += 32) {
    gload16(ga0 + k0, As + 1024 * w);
    gload16(ga1 + k0, As + 1024 * w + 512);
    gload16(gb0 + k0, Bs + 1024 * w);
    gload16(gb1 + k0, Bs + 1024 * w + 512);
    __syncthreads();
    short8 af[4], bf[4];
    #pragma unroll
    for (int i = 0; i < 4; ++i) af[i] = *(const short8*)(As + (wr * 4 + i) * 512 + l * 8);
    #pragma unroll
    for (int j = 0; j < 4; ++j) bf[j] = *(const short8*)(Bs + (wc * 4 + j) * 512 + l * 8);
    #pragma unroll
    for (int i = 0; i < 4; ++i)
      #pragma unroll
      for (int j = 0; j < 4; ++j)
        acc[i][j] = __builtin_amdgcn_mfma_f32_16x16x32_bf16(af[i], bf[j], acc[i][j], 0, 0, 0);
    __syncthreads();
  }
  int colb = n0 + wc * 64 + lr;
  int rowb = sb + wr * 64 + lg * 4;
  #pragma unroll
  for (int i = 0; i < 4; ++i)
    #pragma unroll
    for (int j = 0; j < 4; ++j) {
      int col = colb + j * 16;
      #pragma unroll
      for (int r = 0; r < 4; ++r)
        ob[(size_t)(rowb + i * 16 + r) * 768 + col] = f2bf(acc[i][j][r]);
    }
}

// ---------------------------------------------------------------- attention (f32, register-tiled)
__global__ __launch_bounds__(256) void attn_k(const float* __restrict__ qkv,
                                              unsigned short* __restrict__ ax2, size_t pPS) {
  int pr = blockIdx.x, h = blockIdx.y, b = blockIdx.z;
  int tid = threadIdx.x;
  int ty4 = (tid >> 4) << 2, tx4 = (tid & 15) << 2;
  __shared__ float qs[64][68];    // [d][q]
  __shared__ float kps[64][68];   // [d][k] during QK, then [q][k] = P during PV
  __shared__ float vs[64][68];    // [k][d]
  int lr = tid >> 2;
  int lc = (tid & 3) << 4;
  for (int half = 0; half < 2; ++half) {
    int qt = half ? (15 - pr) : pr;
    int q0 = qt << 6;
    size_t qbase = ((size_t)(b * 1024 + q0 + lr)) * 2304 + h * 64 + lc;
    #pragma unroll
    for (int i = 0; i < 4; ++i) {
      float4 v = *(const float4*)(qkv + qbase + 4 * i);
      qs[lc + 4 * i + 0][lr] = v.x;
      qs[lc + 4 * i + 1][lr] = v.y;
      qs[lc + 4 * i + 2][lr] = v.z;
      qs[lc + 4 * i + 3][lr] = v.w;
    }
    float acc[4][4];
    float m[4], l[4];
    #pragma unroll
    for (int i = 0; i < 4; ++i) {
      m[i] = -3.0e38f; l[i] = 0.0f;
      #pragma unroll
      for (int j = 0; j < 4; ++j) acc[i][j] = 0.0f;
    }
    for (int kt = 0; kt <= qt; ++kt) {
      int k0 = kt << 6;
      __syncthreads();
      size_t kb = ((size_t)(b * 1024 + k0 + lr)) * 2304 + 768 + h * 64 + lc;
      #pragma unroll
      for (int i = 0; i < 4; ++i) {
        float4 kv = *(const float4*)(qkv + kb + 4 * i);
        kps[lc + 4 * i + 0][lr] = kv.x;
        kps[lc + 4 * i + 1][lr] = kv.y;
        kps[lc + 4 * i + 2][lr] = kv.z;
        kps[lc + 4 * i + 3][lr] = kv.w;
        *(float4*)&vs[lr][lc + 4 * i] = *(const float4*)(qkv + kb + 768 + 4 * i);
      }
      __syncthreads();
      float s[4][4];
      #pragma unroll
      for (int i = 0; i < 4; ++i)
        #pragma unroll
        for (int j = 0; j < 4; ++j) s[i][j] = 0.0f;
      #pragma unroll 8
      for (int d = 0; d < 64; ++d) {
        float4 qv = *(const float4*)&qs[d][ty4];
        float4 kv = *(const float4*)&kps[d][tx4];
        float qa[4] = {qv.x, qv.y, qv.z, qv.w};
        float ka[4] = {kv.x, kv.y, kv.z, kv.w};
        #pragma unroll
        for (int i = 0; i < 4; ++i)
          #pragma unroll
          for (int j = 0; j < 4; ++j) s[i][j] += qa[i] * ka[j];
      }
      bool diag = (kt == qt);
      #pragma unroll
      for (int i = 0; i < 4; ++i) {
        #pragma unroll
        for (int j = 0; j < 4; ++j) {
          if (diag && (tx4 + j > ty4 + i)) s[i][j] = -1.0e30f;
          else s[i][j] *= 0.125f;
        }
        float mx = fmaxf(fmaxf(s[i][0], s[i][1]), fmaxf(s[i][2], s[i][3]));
        mx = fmaxf(mx, __shfl_xor(mx, 1));
        mx = fmaxf(mx, __shfl_xor(mx, 2));
        mx = fmaxf(mx, __shfl_xor(mx, 4));
        mx = fmaxf(mx, __shfl_xor(mx, 8));
        float mnew = fmaxf(m[i], mx);
        float c = expf(m[i] - mnew);
        float rs = 0.0f;
        #pragma unroll
        for (int j = 0; j < 4; ++j) { s[i][j] = expf(s[i][j] - mnew); rs += s[i][j]; }
        rs += __shfl_xor(rs, 1);
        rs += __shfl_xor(rs, 2);
        rs += __shfl_xor(rs, 4);
        rs += __shfl_xor(rs, 8);
        l[i] = l[i] * c + rs;
        m[i] = mnew;
        #pragma unroll
        for (int j = 0; j < 4; ++j) acc[i][j] *= c;
      }
      __syncthreads();
      #pragma unroll
      for (int i = 0; i < 4; ++i)
        *(float4*)&kps[ty4 + i][tx4] = make_float4(s[i][0], s[i][1], s[i][2], s[i][3]);
      __syncthreads();
      #pragma unroll 4
      for (int kk = 0; kk < 16; ++kk) {
        float4 v0 = *(const float4*)&vs[(kk << 2) + 0][tx4];
        float4 v1 = *(const float4*)&vs[(kk << 2) + 1][tx4];
        float4 v2 = *(const float4*)&vs[(kk << 2) + 2][tx4];
        float4 v3 = *(const float4*)&vs[(kk << 2) + 3][tx4];
        #pragma unroll
        for (int i = 0; i < 4; ++i) {
          float4 p4 = *(const float4*)&kps[ty4 + i][kk << 2];
          acc[i][0] += p4.x * v0.x + p4.y * v1.x + p4.z * v2.x + p4.w * v3.x;
          acc[i][1] += p4.x * v0.y + p4.y * v1.y + p4.z * v2.y + p4.w * v3.y;
          acc[i][2] += p4.x * v0.z + p4.y * v1.z + p4.z * v2.z + p4.w * v3.z;
          acc[i][3] += p4.x * v0.w + p4.y * v1.w + p4.z * v2.w + p4.w * v3.w;
        }
      }
    }
    __syncthreads();
    #pragma unroll
    for (int i = 0; i < 4; ++i) {
      float invl = 1.0f / l[i];
      size_t ob = ((size_t)(b * 1024 + q0 + ty4 + i)) * 768 + h * 64 + tx4;
      ushort4 vh, vm;
      unsigned short a0, a1;
      split2f(acc[i][0] * invl, a0, a1); vh.x = a0; vm.x = a1;
      split2f(acc[i][1] * invl, a0, a1); vh.y = a0; vm.y = a1;
      split2f(acc[i][2] * invl, a0, a1); vh.z = a0; vm.z = a1;
      split2f(acc[i][3] * invl, a0, a1); vh.w = a0; vm.w = a1;
      *(ushort4*)(ax2 + ob) = vh;
      *(ushort4*)(ax2 + pPS + ob) = vm;
    }
  }
}

// ---------------------------------------------------------------- MoE routing (exact f32)
__global__ __launch_bounds__(256) void router_k(const float* __restrict__ xn,
                                                const float* __restrict__ rw,
                                                int* __restrict__ tk_idx, float* __restrict__ tk_w,
                                                int* __restrict__ cnt, float* __restrict__ psum) {
  __shared__ float bps[8];
  __shared__ int bcnt[8];
  int tid = threadIdx.x;
  if (tid < 8) { bps[tid] = 0.0f; bcnt[tid] = 0; }
  __syncthreads();
  int t = blockIdx.x * 4 + (tid >> 6);
  int lane = tid & 63;
  const float* xr = xn + (size_t)t * 768;
  float p[8] = {};
  for (int d = lane; d < 768; d += 64) {
    float xv = xr[d];
    const float* wr = rw + (size_t)d * 8;
    #pragma unroll
    for (int e = 0; e < 8; ++e) p[e] += xv * wr[e];
  }
  #pragma unroll
  for (int e = 0; e < 8; ++e) {
    float v = p[e];
    #pragma unroll
    for (int o = 32; o > 0; o >>= 1) v += __shfl_xor(v, o);
    p[e] = v;
  }
  if (lane == 0) {
    float mx = p[0];
    #pragma unroll
    for (int e = 1; e < 8; ++e) mx = fmaxf(mx, p[e]);
    float s = 0.0f;
    #pragma unroll
    for (int e = 0; e < 8; ++e) { p[e] = expf(p[e] - mx); s += p[e]; }
    float invs = 1.0f / s;
    #pragma unroll
    for (int e = 0; e < 8; ++e) p[e] *= invs;
    int i1 = 0; float v1 = p[0];
    #pragma unroll
    for (int e = 1; e < 8; ++e) if (p[e] > v1) { v1 = p[e]; i1 = e; }
    int i2 = (i1 == 0) ? 1 : 0; float v2 = p[i2];
    #pragma unroll
    for (int e = 0; e < 8; ++e) if (e != i1 && p[e] > v2) { v2 = p[e]; i2 = e; }
    float wsum = v1 + v2;
    tk_idx[t * 2] = i1; tk_idx[t * 2 + 1] = i2;
    tk_w[t * 2] = v1 / wsum; tk_w[t * 2 + 1] = v2 / wsum;
    atomicAdd(&bcnt[i1], 1); atomicAdd(&bcnt[i2], 1);
    #pragma unroll
    for (int e = 0; e < 8; ++e) atomicAdd(&bps[e], p[e]);
  }
  __syncthreads();
  if (tid < 8) {
    atomicAdd(&cnt[tid], bcnt[tid]);
    atomicAdd(&psum[tid], bps[tid]);
  }
}

__global__ void moe_offsets_k(const int* __restrict__ cnt, int* __restrict__ offs,
                              const float* __restrict__ psum, float* __restrict__ aux) {
  if (threadIdx.x == 0) {
    int o = 0; float a = 0.0f;
    for (int e = 0; e < 8; ++e) {
      offs[e] = o;
      o += (cnt[e] + 127) & ~127;
      a += ((float)cnt[e] / 4096.0f) * (psum[e] / 4096.0f);
    }
    offs[8] = o;
    aux[0] += a * 8.0f;
  }
}

__global__ void moe_fill_k(const int* __restrict__ tk_idx, const int* __restrict__ offs,
                           int* __restrict__ fill, int* __restrict__ slot_token,
                           int* __restrict__ tk_slot) {
  int i = blockIdx.x * 256 + threadIdx.x;              // grid 32
  int e = tk_idx[i];
  int pos = atomicAdd(&fill[e], 1);
  int slot = offs[e] + pos;
  slot_token[slot] = i >> 1;
  tk_slot[i] = slot;
}

template <int BF>  // 0: os f32; 1: os bf16
__global__ void moe_combine_k(float* __restrict__ x, const void* __restrict__ osv,
                              const int* __restrict__ tk_slot, const float* __restrict__ tk_w) {
  int t = blockIdx.x;                                  // grid 4096 x 192
  int d = threadIdx.x << 2;
  int s0 = tk_slot[t * 2], s1 = tk_slot[t * 2 + 1];
  float w0 = tk_w[t * 2], w1 = tk_w[t * 2 + 1];
  float a0, a1, a2, a3, b0, b1, b2, b3;
  if (BF == 0) {
    const float* os = (const float*)osv;
    float4 a = *(const float4*)(os + (size_t)s0 * 768 + d);
    float4 b = *(const float4*)(os + (size_t)s1 * 768 + d);
    a0 = a.x; a1 = a.y; a2 = a.z; a3 = a.w;
    b0 = b.x; b1 = b.y; b2 = b.z; b3 = b.w;
  } else {
    const unsigned short* os = (const unsigned short*)osv;
    ushort4 a = *(const ushort4*)(os + (size_t)s0 * 768 + d);
    ushort4 b = *(const ushort4*)(os + (size_t)s1 * 768 + d);
    a0 = bf2f(a.x); a1 = bf2f(a.y); a2 = bf2f(a.z); a3 = bf2f(a.w);
    b0 = bf2f(b.x); b1 = bf2f(b.y); b2 = bf2f(b.z); b3 = bf2f(b.w);
  }
  float4 c = *(const float4*)(x + (size_t)t * 768 + d);
  c.x += w0 * a0 + w1 * b0;
  c.y += w0 * a1 + w1 * b1;
  c.z += w0 * a2 + w1 * b2;
  c.w += w0 * a3 + w1 * b3;
  *(float4*)(x + (size_t)t * 768 + d) = c;
}

__global__ void write_aux_k(const float* __restrict__ aux, float* __restrict__ out) {
  out[0] = aux[0];
}

// ---------------------------------------------------------------- host launcher

extern "C" void kernel_launch(void* const* d_in, const int* in_sizes, int n_in,
                              void* d_out, int out_size, void* d_ws, size_t ws_size,
                              hipStream_t stream) {
  const int* input_ids      = (const int*)d_in[0];
  const int* time_slots     = (const int*)d_in[1];
  const int* day_of_week    = (const int*)d_in[2];
  const int* month          = (const int*)d_in[3];
  const int* is_holiday     = (const int*)d_in[4];
  const int* location_ids   = (const int*)d_in[5];
  const int* road_types     = (const int*)d_in[6];
  const int* weather_states = (const int*)d_in[7];
  const float* word_emb     = (const float*)d_in[8];
  const float* time_emb     = (const float*)d_in[9];
  const float* dow_emb      = (const float*)d_in[10];
  const float* month_emb    = (const float*)d_in[11];
  const float* hol_emb      = (const float*)d_in[12];
  const float* loc_emb      = (const float*)d_in[13];
  const float* road_emb     = (const float*)d_in[14];
  const float* weather_emb  = (const float*)d_in[15];
  const float* proj_w       = (const float*)d_in[16];
  const float* proj_b       = (const float*)d_in[17];
  const float* emb_norm_w   = (const float*)d_in[18];
  const float* norm1_w      = (const float*)d_in[19];
  const float* Wq           = (const float*)d_in[20];
  const float* Wk           = (const float*)d_in[21];
  const float* Wv           = (const float*)d_in[22];
  const float* Wo           = (const float*)d_in[23];
  const float* norm2_w      = (const float*)d_in[24];
  const float* router_w     = (const float*)d_in[25];
  const float* Wg           = (const float*)d_in[26];
  const float* Wu           = (const float*)d_in[27];
  const float* Wd           = (const float*)d_in[28];
  const float* final_norm_w = (const float*)d_in[29];
  float* out = (float*)d_out;

  const size_t TD = (size_t)TTOK * 768;
  const size_t REG = (size_t)MAXSLOT * FDIM * 4;       // 113.25 MB shared regions
  const size_t HPS = (size_t)MAXSLOT * FDIM;           // h plane stride (elements)
  char* base = (char*)d_ws;
  auto carve = [&](size_t bytes) { char* p = base; base += (bytes + 255) & ~(size_t)255; return p; };
  float* x    = (float*)carve(TD * 4);
  float* xn   = (float*)carve(TD * 4);
  float* cosb = (float*)carve(32768 * 4);
  float* sinb = (float*)carve(32768 * 4);
  float* ctx  = (float*)carve(4 * 1536 * 4);
  float* biasB= (float*)carve(4 * 768 * 4);
  float* tkw  = (float*)carve(8192 * 4);
  float* psum = (float*)carve(64);
  float* auxa = (float*)carve(64);
  int* cnt    = (int*)carve(64);
  int* fill   = (int*)carve(64);
  int* offs   = (int*)carve(64);
  int* tk_idx = (int*)carve(8192 * 4);
  int* tk_slot= (int*)carve(8192 * 4);
  int* slot_token = (int*)carve(MAXSLOT * 4);
  unsigned short* zp = (unsigned short*)carve(4096);
  unsigned short* xnb3 = (unsigned short*)carve(3 * TD * 2);
  char* QAH = carve(REG);                               // qkv+ax2 (attn) / h planes (moe)
  char* GT  = carve(REG);                               // gtmp / g|u halves / ob
  char* Wr  = carve(REG);                               // weight planes (sequential)
  float* qkv = (float*)QAH;
  unsigned short* ax2 = (unsigned short*)(QAH + (size_t)TTOK * 2304 * 4);
  unsigned short* hpl = (unsigned short*)QAH;           // L0: h split-2 planes (2*HPS ushort)
  unsigned short* hb16 = (unsigned short*)QAH;          // L1: h bf16
  float* gtmp = (float*)GT;
  float* obf = (float*)GT;
  unsigned short* gu16 = (unsigned short*)GT;           // L1: g at [0], u at +HPS
  unsigned short* ob16 = (unsigned short*)GT;
  unsigned short* wpl = (unsigned short*)Wr;

  const size_t PS_D = (size_t)768 * 768;
  const size_t PS_QKV = (size_t)2304 * 768;
  const size_t PS_E = (size_t)8 * FDIM * 768;

  hipMemsetAsync(auxa, 0, 64, stream);
  hipMemsetAsync(zp, 0, 4096, stream);
  rope_cache_k<<<dim3(1024), dim3(32), 0, stream>>>(cosb, sinb);
  build_ctx_k<<<dim3(4, 6), dim3(256), 0, stream>>>(time_slots, day_of_week, month, is_holiday,
      location_ids, road_types, weather_states, time_emb, dow_emb, month_emb, hol_emb,
      loc_emb, road_emb, weather_emb, ctx);
  build_bias_k<<<dim3(4, 3), dim3(256), 0, stream>>>(ctx, proj_w, proj_b, biasB);
  tconv3_k<<<dim3(12, 12, 1), dim3(64, 4), 0, stream>>>(proj_w, wpl, PS_D, 768, 768, 0, 0);
  gconv3_k<<<dim3(TTOK), dim3(192), 0, stream>>>(word_emb, input_ids, xnb3, TD);
  gemm3<3><<<dim3(6, 32), dim3(256), 0, stream>>>(xnb3, TD, wpl, PS_D, xn, 768, 768, biasB);
  rmsnorm_k<0><<<dim3(TTOK), dim3(256), 0, stream>>>(xn, emb_norm_w, x, nullptr, 0);

  for (int l = 0; l < 2; ++l) {
    const float* rw = router_w + (size_t)l * 768 * 8;
    // ---- attention (split-2 GEMMs, f32 flash core) ----
    tconv2_k<<<dim3(12, 12, 1), dim3(64, 4), 0, stream>>>(Wq + (size_t)l * PS_D, wpl, PS_QKV, 768, 768, 0, 0);
    tconv2_k<<<dim3(12, 12, 1), dim3(64, 4), 0, stream>>>(Wk + (size_t)l * PS_D, wpl + PS_D, PS_QKV, 768, 768, 0, 0);
    tconv2_k<<<dim3(12, 12, 1), dim3(64, 4), 0, stream>>>(Wv + (size_t)l * PS_D, wpl + 2 * PS_D, PS_QKV, 768, 768, 0, 0);
    rmsnorm_k<1><<<dim3(TTOK), dim3(256), 0, stream>>>(x, norm1_w + l * 768, nullptr, xnb3, TD);
    gemm2<0><<<dim3(18, 32), dim3(256), 0, stream>>>(xnb3, TD, wpl, PS_QKV, qkv, 2304, 768);
    rope_apply_k<<<dim3(6144), dim3(256), 0, stream>>>(qkv, cosb, sinb);
    attn_k<<<dim3(8, 12, 4), dim3(256), 0, stream>>>(qkv, ax2, TD);
    tconv2_k<<<dim3(12, 12, 1), dim3(64, 4), 0, stream>>>(Wo + (size_t)l * PS_D, wpl, PS_D, 768, 768, 0, 0);
    gemm2<2><<<dim3(6, 32), dim3(256), 0, stream>>>(ax2, TD, wpl, PS_D, x, 768, 768);

    // ---- MoE ----
    if (l == 0)
      rmsnorm_k<2><<<dim3(TTOK), dim3(256), 0, stream>>>(x, norm2_w, xn, xnb3, TD);
    else
      rmsnorm_k<3><<<dim3(TTOK), dim3(256), 0, stream>>>(x, norm2_w + 768, xn, xnb3, TD);
    hipMemsetAsync(cnt, 0, 64, stream);
    hipMemsetAsync(fill, 0, 64, stream);
    hipMemsetAsync(psum, 0, 64, stream);
    hipMemsetAsync(slot_token, 0xFF, MAXSLOT * 4, stream);
    router_k<<<dim3(1024), dim3(256), 0, stream>>>(xn, rw, tk_idx, tkw, cnt, psum);
    moe_offsets_k<<<dim3(1), dim3(64), 0, stream>>>(cnt, offs, psum, auxa);
    moe_fill_k<<<dim3(32), dim3(256), 0, stream>>>(tk_idx, offs, fill, slot_token, tk_slot);
    if (l == 0) {
      // split-2 experts; XCD-chunked grids
      tconv2_k<<<dim3(48, 12, 8), dim3(64, 4), 0, stream>>>(Wg, wpl, PS_E,
          768, FDIM, (size_t)768 * FDIM, (size_t)FDIM * 768);
      gemm2_gu<0><<<dim3(1728), dim3(256), 0, stream>>>(xnb3, TD, wpl, PS_E,
          gtmp, nullptr, 0, nullptr, slot_token, offs, zp);
      tconv2_k<<<dim3(48, 12, 8), dim3(64, 4), 0, stream>>>(Wu, wpl, PS_E,
          768, FDIM, (size_t)768 * FDIM, (size_t)FDIM * 768);
      gemm2_gu<1><<<dim3(1728), dim3(256), 0, stream>>>(xnb3, TD, wpl, PS_E,
          nullptr, hpl, HPS, gtmp, slot_token, offs, zp);
      tconv2_k<<<dim3(12, 48, 8), dim3(64, 4), 0, stream>>>(Wd, wpl, PS_E,
          FDIM, 768, (size_t)FDIM * 768, (size_t)768 * FDIM);
      gemm2_dn<<<dim3(432), dim3(256), 0, stream>>>(hpl, HPS, wpl, PS_E, obf, offs);
      moe_combine_k<0><<<dim3(TTOK), dim3(192), 0, stream>>>(x, obf, tk_slot, tkw);
    } else {
      // plain bf16 experts; XCD-chunked grids
      const float* wg1 = Wg + (size_t)8 * 768 * FDIM;
      const float* wu1 = Wu + (size_t)8 * 768 * FDIM;
      const float* wd1 = Wd + (size_t)8 * FDIM * 768;
      tconv_k<<<dim3(48, 12, 8), dim3(64, 4), 0, stream>>>(wg1, wpl,
          768, FDIM, (size_t)768 * FDIM, (size_t)FDIM * 768);
      tconv_k<<<dim3(48, 12, 8), dim3(64, 4), 0, stream>>>(wu1, wpl + PS_E,
          768, FDIM, (size_t)768 * FDIM, (size_t)FDIM * 768);
      gemm_gu2<<<dim3(3456), dim3(256), 0, stream>>>(xnb3, wpl, wpl + PS_E,
          gu16, slot_token, offs, zp);
      silu_mul_k<<<dim3((int)((size_t)MAXSLOT * FDIM / 2048)), dim3(256), 0, stream>>>(gu16, hb16);
      tconv_k<<<dim3(12, 48, 8), dim3(64, 4), 0, stream>>>(wd1, wpl,
          FDIM, 768, (size_t)FDIM * 768, (size_t)768 * FDIM);
      gemm_d<<<dim3(432), dim3(256), 0, stream>>>(hb16, wpl, ob16, offs);
      moe_combine_k<1><<<dim3(TTOK), dim3(192), 0, stream>>>(x, ob16, tk_slot, tkw);
    }
  }

  rmsnorm_k<0><<<dim3(TTOK), dim3(256), 0, stream>>>(x, final_norm_w, out, nullptr, 0);
  write_aux_k<<<dim3(1), dim3(1), 0, stream>>>(auxa, out + TD);
}

// Round 8
// 2137.636 us; speedup vs baseline: 1.0116x; 1.0116x over previous
//
#include <hip/hip_runtime.h>
#include <math.h>

// Traffic foundation model, round 7 (bit-identical numerics vs r5/r6):
// REVERT r6's XCD-chunk swizzle on expert GEMMs (it increased FETCH 197->260MB:
// the r5 2D grid (n fastest, 24%8==0) already put same-n0 blocks on one XCD and
// kept same-sb activation rows temporally co-resident). KEEP r6's 64x64 tconvs
// and the h-as-split2-planes path for gemm2_dn (net ~-33us, bit-identical).
// Precision map (validated r2-r5): proj split-3; QKV/Wo/L0-experts split-2
// (17-bit); router exact f32; attn f32 core; L1 experts plain bf16.

#define TTOK 4096
#define FDIM 3072
#define MAXSLOT 9216   // 8192 + 8*127 pad, 128-aligned offsets; 72 sb-blocks

typedef __attribute__((ext_vector_type(8))) short short8;
typedef __attribute__((ext_vector_type(4))) float f32x4;

__device__ __forceinline__ float bf2f(unsigned short u) {
  return __uint_as_float(((unsigned int)u) << 16);
}
__device__ __forceinline__ unsigned short f2bf(float f) {
  unsigned int u = __float_as_uint(f);
  u += 0x7fffu + ((u >> 16) & 1u);
  return (unsigned short)(u >> 16);
}
__device__ __forceinline__ void split3f(float a, unsigned short& h, unsigned short& m,
                                        unsigned short& l) {
  h = f2bf(a);
  float r = a - bf2f(h);
  m = f2bf(r);
  r -= bf2f(m);
  l = f2bf(r);
}
__device__ __forceinline__ void split2f(float a, unsigned short& h, unsigned short& m) {
  h = f2bf(a);
  m = f2bf(a - bf2f(h));
}
__device__ __forceinline__ void gload16(const void* g, void* l) {
  __builtin_amdgcn_global_load_lds((const __attribute__((address_space(1))) unsigned int*)g,
                                   (__attribute__((address_space(3))) unsigned int*)l, 16, 0, 0);
}

#define MFMA_TERM(ACC, PA, PB)                                                              \
  _Pragma("unroll") for (int i_ = 0; i_ < 4; ++i_)                                          \
      _Pragma("unroll") for (int j_ = 0; j_ < 4; ++j_)                                      \
          ACC[i_][j_] = __builtin_amdgcn_mfma_f32_16x16x32_bf16(af[PA][i_], bf[PB][j_],     \
                                                                ACC[i_][j_], 0, 0, 0);
#define MFMA_SPLIT3(ACC)  \
  MFMA_TERM(ACC, 0, 2) MFMA_TERM(ACC, 2, 0) MFMA_TERM(ACC, 1, 1) \
  MFMA_TERM(ACC, 0, 1) MFMA_TERM(ACC, 1, 0) MFMA_TERM(ACC, 0, 0)
#define MFMA_SPLIT2(ACC)  \
  MFMA_TERM(ACC, 0, 1) MFMA_TERM(ACC, 1, 0) MFMA_TERM(ACC, 0, 0)

// ---------------------------------------------------------------- small kernels

__global__ void rope_cache_k(float* __restrict__ cosb, float* __restrict__ sinb) {
  int s = blockIdx.x, i = threadIdx.x;                 // grid 1024 x 32
  float inv = powf(10000.0f, -(float)i / 32.0f);
  float a = (float)s * inv;
  cosb[s * 32 + i] = cosf(a);
  sinb[s * 32 + i] = sinf(a);
}

__global__ void build_ctx_k(const int* ts, const int* dow, const int* mon, const int* hol,
                            const int* loc, const int* road, const int* wth,
                            const float* te, const float* de, const float* me, const float* he,
                            const float* le, const float* re, const float* we,
                            float* __restrict__ ctx) {
  int b = blockIdx.x;
  int j = blockIdx.y * 256 + threadIdx.x;              // grid (4,6) x 256
  float v;
  if (j < 192)       v = te[ts[b] * 192 + j];
  else if (j < 384)  v = de[dow[b] * 192 + (j - 192)];
  else if (j < 576)  v = me[mon[b] * 192 + (j - 384)];
  else if (j < 768)  v = he[hol[b] * 192 + (j - 576)];
  else if (j < 1152) v = le[loc[b] * 384 + (j - 768)];
  else if (j < 1344) v = re[road[b] * 192 + (j - 1152)];
  else               v = we[wth[b] * 192 + (j - 1344)];
  ctx[b * 1536 + j] = v;
}

__global__ void build_bias_k(const float* __restrict__ ctx, const float* __restrict__ pw,
                             const float* __restrict__ pb, float* __restrict__ biasB) {
  int b = blockIdx.x;
  int d = blockIdx.y * 256 + threadIdx.x;              // grid (4,3) x 256
  float s = pb[d];
  const float* cb = ctx + b * 1536;
  for (int j = 0; j < 1536; ++j) s += cb[j] * pw[(size_t)(768 + j) * 768 + d];
  biasB[b * 768 + d] = s;
}

// ---- transpose kernels: 64x64 tiles, block (64,4), 128B-coalesced both sides ----

__global__ void tconv3_k(const float* __restrict__ src, unsigned short* __restrict__ dst,
                         size_t dPS, int K, int N, size_t sstride, size_t dstride) {
  __shared__ float tile[64][65];
  src += (size_t)blockIdx.z * sstride;
  size_t dbase = (size_t)blockIdx.z * dstride;
  int n0 = blockIdx.x * 64, k0 = blockIdx.y * 64;
  int tx = threadIdx.x, ty = threadIdx.y;
  #pragma unroll
  for (int r = 0; r < 16; ++r)
    tile[ty + r * 4][tx] = src[(size_t)(k0 + ty + r * 4) * N + n0 + tx];
  __syncthreads();
  #pragma unroll
  for (int r = 0; r < 16; ++r) {
    int n = n0 + ty + r * 4;
    unsigned short h, m, lo;
    split3f(tile[tx][ty + r * 4], h, m, lo);
    size_t di = dbase + (size_t)n * K + k0 + tx;
    dst[di] = h; dst[di + dPS] = m; dst[di + 2 * dPS] = lo;
  }
}

__global__ void tconv2_k(const float* __restrict__ src, unsigned short* __restrict__ dst,
                         size_t dPS, int K, int N, size_t sstride, size_t dstride) {
  __shared__ float tile[64][65];
  src += (size_t)blockIdx.z * sstride;
  size_t dbase = (size_t)blockIdx.z * dstride;
  int n0 = blockIdx.x * 64, k0 = blockIdx.y * 64;
  int tx = threadIdx.x, ty = threadIdx.y;
  #pragma unroll
  for (int r = 0; r < 16; ++r)
    tile[ty + r * 4][tx] = src[(size_t)(k0 + ty + r * 4) * N + n0 + tx];
  __syncthreads();
  #pragma unroll
  for (int r = 0; r < 16; ++r) {
    int n = n0 + ty + r * 4;
    unsigned short h, m;
    split2f(tile[tx][ty + r * 4], h, m);
    size_t di = dbase + (size_t)n * K + k0 + tx;
    dst[di] = h; dst[di + dPS] = m;
  }
}

__global__ void tconv_k(const float* __restrict__ src, unsigned short* __restrict__ dst,
                        int K, int N, size_t sstride, size_t dstride) {
  __shared__ float tile[64][65];
  src += (size_t)blockIdx.z * sstride;
  unsigned short* d = dst + (size_t)blockIdx.z * dstride;
  int n0 = blockIdx.x * 64, k0 = blockIdx.y * 64;
  int tx = threadIdx.x, ty = threadIdx.y;
  #pragma unroll
  for (int r = 0; r < 16; ++r)
    tile[ty + r * 4][tx] = src[(size_t)(k0 + ty + r * 4) * N + n0 + tx];
  __syncthreads();
  #pragma unroll
  for (int r = 0; r < 16; ++r) {
    int n = n0 + ty + r * 4;
    d[(size_t)n * K + k0 + tx] = f2bf(tile[tx][ty + r * 4]);
  }
}

// gather word_emb rows -> 3 planes. grid 4096 x 192
__global__ void gconv3_k(const float* __restrict__ we, const int* __restrict__ ids,
                         unsigned short* __restrict__ x3, size_t pPS) {
  int t = blockIdx.x;
  int d = threadIdx.x << 2;
  float4 v = *(const float4*)(we + (size_t)ids[t] * 768 + d);
  ushort4 vh, vm, vl;
  split3f(v.x, vh.x, vm.x, vl.x);
  split3f(v.y, vh.y, vm.y, vl.y);
  split3f(v.z, vh.z, vm.z, vl.z);
  split3f(v.w, vh.w, vm.w, vl.w);
  size_t o = (size_t)t * 768 + d;
  *(ushort4*)(x3 + o) = vh;
  *(ushort4*)(x3 + pPS + o) = vm;
  *(ushort4*)(x3 + 2 * pPS + o) = vl;
}

// OUT: 0 f32 only; 1 2-plane only; 2 f32 + 2-plane; 3 f32 + single-bf16(plane0)
template <int OUT>
__global__ __launch_bounds__(256) void rmsnorm_k(const float* __restrict__ xin,
                                                 const float* __restrict__ w,
                                                 float* __restrict__ yf,
                                                 unsigned short* __restrict__ yb, size_t pPS) {
  int t = blockIdx.x;
  int tid = threadIdx.x;
  const float* xr = xin + (size_t)t * 768;
  float v0 = xr[tid], v1 = xr[tid + 256], v2 = xr[tid + 512];
  float ss = v0 * v0 + v1 * v1 + v2 * v2;
  #pragma unroll
  for (int o = 32; o > 0; o >>= 1) ss += __shfl_xor(ss, o);
  __shared__ float wss[4];
  if ((tid & 63) == 0) wss[tid >> 6] = ss;
  __syncthreads();
  float tot = wss[0] + wss[1] + wss[2] + wss[3];
  float inv = 1.0f / sqrtf(tot / 768.0f + 1e-6f);
  float o0 = v0 * inv * w[tid], o1 = v1 * inv * w[tid + 256], o2 = v2 * inv * w[tid + 512];
  if (OUT != 1) {
    float* yr = yf + (size_t)t * 768;
    yr[tid] = o0; yr[tid + 256] = o1; yr[tid + 512] = o2;
  }
  if (OUT == 1 || OUT == 2) {
    unsigned short* yr = yb + (size_t)t * 768;
    unsigned short h, m;
    split2f(o0, h, m); yr[tid] = h;       yr[tid + pPS] = m;
    split2f(o1, h, m); yr[tid + 256] = h; yr[tid + 256 + pPS] = m;
    split2f(o2, h, m); yr[tid + 512] = h; yr[tid + 512 + pPS] = m;
  }
  if (OUT == 3) {
    unsigned short* yr = yb + (size_t)t * 768;
    yr[tid] = f2bf(o0); yr[tid + 256] = f2bf(o1); yr[tid + 512] = f2bf(o2);
  }
}

// rope in-place on f32 qkv [T][2304] (q at 0, k at 768)
__global__ __launch_bounds__(256) void rope_apply_k(float* __restrict__ qkv,
                                                    const float* __restrict__ cosb,
                                                    const float* __restrict__ sinb) {
  int idx = blockIdx.x * 256 + threadIdx.x;            // grid 6144
  int j = idx & 31;
  int hh = (idx >> 5) % 12;
  int t = idx / 384;
  int s = t & 1023;
  float c = cosb[s * 32 + j], sn = sinb[s * 32 + j];
  size_t base = (size_t)t * 2304 + hh * 64 + j;
  float q1 = qkv[base], q2 = qkv[base + 32];
  qkv[base]      = q1 * c - q2 * sn;
  qkv[base + 32] = q2 * c + q1 * sn;
  size_t kb = base + 768;
  float k1 = qkv[kb], k2 = qkv[kb + 32];
  qkv[kb]      = k1 * c - k2 * sn;
  qkv[kb + 32] = k2 * c + k1 * sn;
}

// ---------------------------------------------------------------- split-3 dense GEMM (proj only)
template <int EPI>
__global__ __launch_bounds__(256) void gemm3(const unsigned short* __restrict__ A, size_t aPS,
                                             const unsigned short* __restrict__ BT, size_t bPS,
                                             float* __restrict__ Cf, int N, int K,
                                             const float* __restrict__ rowBias) {
  __shared__ __align__(16) unsigned short As[3][4096];
  __shared__ __align__(16) unsigned short Bs[3][4096];
  int tid = threadIdx.x, w = tid >> 6, l = tid & 63, lr = l & 15, lg = l >> 4;
  int m0 = blockIdx.y * 128, n0 = blockIdx.x * 128;
  size_t aoff = (size_t)(m0 + 32 * w + lr) * K + lg * 8;
  size_t boff = (size_t)(n0 + 32 * w + lr) * K + lg * 8;
  size_t aoff1 = aoff + (size_t)16 * K, boff1 = boff + (size_t)16 * K;
  f32x4 acc[4][4];
  #pragma unroll
  for (int i = 0; i < 4; ++i)
    #pragma unroll
    for (int j = 0; j < 4; ++j) acc[i][j] = (f32x4){0.f, 0.f, 0.f, 0.f};
  int wr = w >> 1, wc = w & 1;
  for (int k0 = 0; k0 < K; k0 += 32) {
    #pragma unroll
    for (int p = 0; p < 3; ++p) {
      gload16(A + p * aPS + aoff + k0,  &As[p][1024 * w]);
      gload16(A + p * aPS + aoff1 + k0, &As[p][1024 * w + 512]);
      gload16(BT + p * bPS + boff + k0,  &Bs[p][1024 * w]);
      gload16(BT + p * bPS + boff1 + k0, &Bs[p][1024 * w + 512]);
    }
    __syncthreads();
    short8 af[3][4], bf[3][4];
    #pragma unroll
    for (int p = 0; p < 3; ++p)
      #pragma unroll
      for (int i = 0; i < 4; ++i) {
        af[p][i] = *(const short8*)(&As[p][(wr * 4 + i) * 512 + l * 8]);
        bf[p][i] = *(const short8*)(&Bs[p][(wc * 4 + i) * 512 + l * 8]);
      }
    MFMA_SPLIT3(acc)
    __syncthreads();
  }
  int colb = n0 + wc * 64 + lr;
  int rowb = m0 + wr * 64 + lg * 4;
  #pragma unroll
  for (int i = 0; i < 4; ++i)
    #pragma unroll
    for (int j = 0; j < 4; ++j) {
      int col = colb + j * 16;
      #pragma unroll
      for (int r = 0; r < 4; ++r) {
        int row = rowb + i * 16 + r;
        size_t idx = (size_t)row * N + col;
        float v = acc[i][j][r];
        if (EPI == 0)      Cf[idx] = v;
        else if (EPI == 2) Cf[idx] += v;
        else               Cf[idx] = v + rowBias[(row >> 10) * 768 + col];
      }
    }
}

// ---------------------------------------------------------------- split-2 dense GEMM (QKV, Wo)
template <int EPI>  // 0: f32 store; 2: f32 +=
__global__ __launch_bounds__(256) void gemm2(const unsigned short* __restrict__ A, size_t aPS,
                                             const unsigned short* __restrict__ BT, size_t bPS,
                                             float* __restrict__ Cf, int N, int K) {
  __shared__ __align__(16) unsigned short As[2][4096];
  __shared__ __align__(16) unsigned short Bs[2][4096];
  int tid = threadIdx.x, w = tid >> 6, l = tid & 63, lr = l & 15, lg = l >> 4;
  int m0 = blockIdx.y * 128, n0 = blockIdx.x * 128;
  size_t aoff = (size_t)(m0 + 32 * w + lr) * K + lg * 8;
  size_t boff = (size_t)(n0 + 32 * w + lr) * K + lg * 8;
  size_t aoff1 = aoff + (size_t)16 * K, boff1 = boff + (size_t)16 * K;
  f32x4 acc[4][4];
  #pragma unroll
  for (int i = 0; i < 4; ++i)
    #pragma unroll
    for (int j = 0; j < 4; ++j) acc[i][j] = (f32x4){0.f, 0.f, 0.f, 0.f};
  int wr = w >> 1, wc = w & 1;
  for (int k0 = 0; k0 < K; k0 += 32) {
    #pragma unroll
    for (int p = 0; p < 2; ++p) {
      gload16(A + p * aPS + aoff + k0,  &As[p][1024 * w]);
      gload16(A + p * aPS + aoff1 + k0, &As[p][1024 * w + 512]);
      gload16(BT + p * bPS + boff + k0,  &Bs[p][1024 * w]);
      gload16(BT + p * bPS + boff1 + k0, &Bs[p][1024 * w + 512]);
    }
    __syncthreads();
    short8 af[2][4], bf[2][4];
    #pragma unroll
    for (int p = 0; p < 2; ++p)
      #pragma unroll
      for (int i = 0; i < 4; ++i) {
        af[p][i] = *(const short8*)(&As[p][(wr * 4 + i) * 512 + l * 8]);
        bf[p][i] = *(const short8*)(&Bs[p][(wc * 4 + i) * 512 + l * 8]);
      }
    MFMA_SPLIT2(acc)
    __syncthreads();
  }
  int colb = n0 + wc * 64 + lr;
  int rowb = m0 + wr * 64 + lg * 4;
  #pragma unroll
  for (int i = 0; i < 4; ++i)
    #pragma unroll
    for (int j = 0; j < 4; ++j) {
      int col = colb + j * 16;
      #pragma unroll
      for (int r = 0; r < 4; ++r) {
        int row = rowb + i * 16 + r;
        size_t idx = (size_t)row * N + col;
        float v = acc[i][j][r];
        if (EPI == 0) Cf[idx] = v;
        else          Cf[idx] += v;
      }
    }
}

// ---------------------------------------------------------------- L0 experts (split-2)
// 2D grid (24, 72): n fastest; 24%8==0 keeps same-n0 blocks on one XCD (weight L2 reuse)
// while same-sb blocks run concurrently (activation reuse). [r6 swizzle reverted]
// FUSE 0: g-pass, store f32 gtmp. FUSE 1: u-pass, h=silu(g)*u -> split-2 planes.
template <int FUSE>
__global__ __launch_bounds__(256) void gemm2_gu(const unsigned short* __restrict__ X3, size_t xPS,
    const unsigned short* __restrict__ W2, size_t wPS, float* __restrict__ gout,
    unsigned short* __restrict__ hout, size_t hPS, const float* __restrict__ gin,
    const int* __restrict__ slot_token, const int* __restrict__ offs,
    const unsigned short* __restrict__ zp) {
  __shared__ __align__(16) unsigned short As[2][4096];
  __shared__ __align__(16) unsigned short Bs[2][4096];
  int sb = blockIdx.y * 128;
  int n0 = blockIdx.x * 128;
  if (sb >= offs[8]) return;
  int e = 0;
  #pragma unroll
  for (int i = 1; i < 8; ++i) if (sb >= offs[i]) e = i;
  int tid = threadIdx.x, w = tid >> 6, l = tid & 63, lr = l & 15, lg = l >> 4;
  const unsigned short* WE = W2 + (size_t)e * FDIM * 768;
  int t0 = slot_token[sb + 32 * w + lr];
  int t1 = slot_token[sb + 32 * w + 16 + lr];
  const unsigned short* a0[2];
  const unsigned short* a1[2];
  #pragma unroll
  for (int p = 0; p < 2; ++p) {
    a0[p] = (t0 < 0 ? zp : X3 + p * xPS + (size_t)t0 * 768) + lg * 8;
    a1[p] = (t1 < 0 ? zp : X3 + p * xPS + (size_t)t1 * 768) + lg * 8;
  }
  size_t boff = (size_t)(n0 + 32 * w + lr) * 768 + lg * 8;
  size_t boff1 = boff + (size_t)16 * 768;
  f32x4 acc[4][4];
  #pragma unroll
  for (int i = 0; i < 4; ++i)
    #pragma unroll
    for (int j = 0; j < 4; ++j) acc[i][j] = (f32x4){0.f, 0.f, 0.f, 0.f};
  int wr = w >> 1, wc = w & 1;
  for (int k0 = 0; k0 < 768; k0 += 32) {
    #pragma unroll
    for (int p = 0; p < 2; ++p) {
      gload16(a0[p] + k0, &As[p][1024 * w]);
      gload16(a1[p] + k0, &As[p][1024 * w + 512]);
      gload16(WE + p * wPS + boff + k0,  &Bs[p][1024 * w]);
      gload16(WE + p * wPS + boff1 + k0, &Bs[p][1024 * w + 512]);
    }
    __syncthreads();
    short8 af[2][4], bf[2][4];
    #pragma unroll
    for (int p = 0; p < 2; ++p)
      #pragma unroll
      for (int i = 0; i < 4; ++i) {
        af[p][i] = *(const short8*)(&As[p][(wr * 4 + i) * 512 + l * 8]);
        bf[p][i] = *(const short8*)(&Bs[p][(wc * 4 + i) * 512 + l * 8]);
      }
    MFMA_SPLIT2(acc)
    __syncthreads();
  }
  int colb = n0 + wc * 64 + lr;
  int rowb = sb + wr * 64 + lg * 4;
  #pragma unroll
  for (int i = 0; i < 4; ++i)
    #pragma unroll
    for (int j = 0; j < 4; ++j) {
      int col = colb + j * 16;
      #pragma unroll
      for (int r = 0; r < 4; ++r) {
        size_t idx = (size_t)(rowb + i * 16 + r) * FDIM + col;
        float v = acc[i][j][r];
        if (FUSE == 0) gout[idx] = v;
        else {
          float g = gin[idx];
          float h = g / (1.0f + expf(-g)) * v;         // silu(g)*u
          unsigned short hh, hm;
          split2f(h, hh, hm);
          hout[idx] = hh; hout[idx + hPS] = hm;
        }
      }
    }
}

// L0 down: A = h split-2 planes (direct gload16), B = wd 2 planes. N=768, K=3072.
// 2D grid (6, 72).
__global__ __launch_bounds__(256) void gemm2_dn(const unsigned short* __restrict__ hpl, size_t hPS,
    const unsigned short* __restrict__ W2, size_t wPS, float* __restrict__ ob,
    const int* __restrict__ offs) {
  __shared__ __align__(16) unsigned short As[2][4096];
  __shared__ __align__(16) unsigned short Bs[2][4096];
  int sb = blockIdx.y * 128;
  int n0 = blockIdx.x * 128;
  if (sb >= offs[8]) return;
  int e = 0;
  #pragma unroll
  for (int i = 1; i < 8; ++i) if (sb >= offs[i]) e = i;
  int tid = threadIdx.x, w = tid >> 6, l = tid & 63, lr = l & 15, lg = l >> 4;
  const unsigned short* WE = W2 + (size_t)e * 768 * FDIM;
  size_t aoff = (size_t)(sb + 32 * w + lr) * FDIM + lg * 8;
  size_t aoff1 = aoff + (size_t)16 * FDIM;
  size_t boff = (size_t)(n0 + 32 * w + lr) * FDIM + lg * 8;
  size_t boff1 = boff + (size_t)16 * FDIM;
  f32x4 acc[4][4];
  #pragma unroll
  for (int i = 0; i < 4; ++i)
    #pragma unroll
    for (int j = 0; j < 4; ++j) acc[i][j] = (f32x4){0.f, 0.f, 0.f, 0.f};
  int wr = w >> 1, wc = w & 1;
  for (int k0 = 0; k0 < FDIM; k0 += 32) {
    #pragma unroll
    for (int p = 0; p < 2; ++p) {
      gload16(hpl + p * hPS + aoff + k0,  &As[p][1024 * w]);
      gload16(hpl + p * hPS + aoff1 + k0, &As[p][1024 * w + 512]);
      gload16(WE + p * wPS + boff + k0,  &Bs[p][1024 * w]);
      gload16(WE + p * wPS + boff1 + k0, &Bs[p][1024 * w + 512]);
    }
    __syncthreads();
    short8 af[2][4], bf[2][4];
    #pragma unroll
    for (int p = 0; p < 2; ++p)
      #pragma unroll
      for (int i = 0; i < 4; ++i) {
        af[p][i] = *(const short8*)(&As[p][(wr * 4 + i) * 512 + l * 8]);
        bf[p][i] = *(const short8*)(&Bs[p][(wc * 4 + i) * 512 + l * 8]);
      }
    MFMA_SPLIT2(acc)
    __syncthreads();
  }
  int colb = n0 + wc * 64 + lr;
  int rowb = sb + wr * 64 + lg * 4;
  #pragma unroll
  for (int i = 0; i < 4; ++i)
    #pragma unroll
    for (int j = 0; j < 4; ++j) {
      int col = colb + j * 16;
      #pragma unroll
      for (int r = 0; r < 4; ++r)
        ob[(size_t)(rowb + i * 16 + r) * 768 + col] = acc[i][j][r];
    }
}

// ---------------------------------------------------------------- L1 experts (plain bf16)
// N-concat gate+up, 2D grid (48, 72): n fastest, 48%8==0 -> same-n0 same-XCD.
__global__ __launch_bounds__(256) void gemm_gu2(const unsigned short* __restrict__ xnb,
    const unsigned short* __restrict__ wgT, const unsigned short* __restrict__ wuT,
    unsigned short* __restrict__ gub, const int* __restrict__ slot_token,
    const int* __restrict__ offs, const unsigned short* __restrict__ zp) {
  __shared__ __align__(16) unsigned short As[4096], Bs[4096];
  int sb = blockIdx.y * 128;
  int n0 = blockIdx.x * 128;
  if (sb >= offs[8]) return;
  int e = 0;
  #pragma unroll
  for (int i = 1; i < 8; ++i) if (sb >= offs[i]) e = i;
  int tid = threadIdx.x, w = tid >> 6, l = tid & 63, lr = l & 15, lg = l >> 4;
  int nl = (n0 < FDIM) ? n0 : (n0 - FDIM);
  const unsigned short* WE = ((n0 < FDIM) ? wgT : wuT) + (size_t)e * FDIM * 768;
  unsigned short* OB = (n0 < FDIM) ? gub : (gub + (size_t)MAXSLOT * FDIM);
  int t0 = slot_token[sb + 32 * w + lr];
  int t1 = slot_token[sb + 32 * w + 16 + lr];
  const unsigned short* ga0 = (t0 < 0 ? zp : xnb + (size_t)t0 * 768) + lg * 8;
  const unsigned short* ga1 = (t1 < 0 ? zp : xnb + (size_t)t1 * 768) + lg * 8;
  const unsigned short* gb0 = WE + (size_t)(nl + 32 * w + lr) * 768 + lg * 8;
  const unsigned short* gb1 = gb0 + 16 * 768;
  f32x4 acc[4][4];
  #pragma unroll
  for (int i = 0; i < 4; ++i)
    #pragma unroll
    for (int j = 0; j < 4; ++j) acc[i][j] = (f32x4){0.f, 0.f, 0.f, 0.f};
  int wr = w >> 1, wc = w & 1;
  for (int k0 = 0; k0 < 768; k0 += 32) {
    gload16(ga0 + k0, As + 1024 * w);
    gload16(ga1 + k0, As + 1024 * w + 512);
    gload16(gb0 + k0, Bs + 1024 * w);
    gload16(gb1 + k0, Bs + 1024 * w + 512);
    __syncthreads();
    short8 af[4], bf[4];
    #pragma unroll
    for (int i = 0; i < 4; ++i) af[i] = *(const short8*)(As + (wr * 4 + i) * 512 + l * 8);
    #pragma unroll
    for (int j = 0; j < 4; ++j) bf[j] = *(const short8*)(Bs + (wc * 4 + j) * 512 + l * 8);
    #pragma unroll
    for (int i = 0; i < 4; ++i)
      #pragma unroll
      for (int j = 0; j < 4; ++j)
        acc[i][j] = __builtin_amdgcn_mfma_f32_16x16x32_bf16(af[i], bf[j], acc[i][j], 0, 0, 0);
    __syncthreads();
  }
  int colb = nl + wc * 64 + lr;
  int rowb = sb + wr * 64 + lg * 4;
  #pragma unroll
  for (int i = 0; i < 4; ++i)
    #pragma unroll
    for (int j = 0; j < 4; ++j) {
      int col = colb + j * 16;
      #pragma unroll
      for (int r = 0; r < 4; ++r)
        OB[(size_t)(rowb + i * 16 + r) * FDIM + col] = f2bf(acc[i][j][r]);
    }
}

// h = silu(g) * u, bf16 in/out. grid 13824 x 256 (8 elems/thread over MAXSLOT*FDIM)
__global__ void silu_mul_k(const unsigned short* __restrict__ gub,
                           unsigned short* __restrict__ hb) {
  size_t i = ((size_t)blockIdx.x * 256 + threadIdx.x) * 8;
  const unsigned short* u = gub + (size_t)MAXSLOT * FDIM;
  ushort4 g0 = *(const ushort4*)(gub + i);
  ushort4 g1 = *(const ushort4*)(gub + i + 4);
  ushort4 u0 = *(const ushort4*)(u + i);
  ushort4 u1 = *(const ushort4*)(u + i + 4);
  float gf[8] = {bf2f(g0.x), bf2f(g0.y), bf2f(g0.z), bf2f(g0.w),
                 bf2f(g1.x), bf2f(g1.y), bf2f(g1.z), bf2f(g1.w)};
  float uf[8] = {bf2f(u0.x), bf2f(u0.y), bf2f(u0.z), bf2f(u0.w),
                 bf2f(u1.x), bf2f(u1.y), bf2f(u1.z), bf2f(u1.w)};
  ushort4 h0, h1;
  h0.x = f2bf(gf[0] / (1.0f + expf(-gf[0])) * uf[0]);
  h0.y = f2bf(gf[1] / (1.0f + expf(-gf[1])) * uf[1]);
  h0.z = f2bf(gf[2] / (1.0f + expf(-gf[2])) * uf[2]);
  h0.w = f2bf(gf[3] / (1.0f + expf(-gf[3])) * uf[3]);
  h1.x = f2bf(gf[4] / (1.0f + expf(-gf[4])) * uf[4]);
  h1.y = f2bf(gf[5] / (1.0f + expf(-gf[5])) * uf[5]);
  h1.z = f2bf(gf[6] / (1.0f + expf(-gf[6])) * uf[6]);
  h1.w = f2bf(gf[7] / (1.0f + expf(-gf[7])) * uf[7]);
  *(ushort4*)(hb + i) = h0;
  *(ushort4*)(hb + i + 4) = h1;
}

// L1 down (plain bf16), 2D grid (6, 72).
__global__ __launch_bounds__(256) void gemm_d(const unsigned short* __restrict__ hb,
    const unsigned short* __restrict__ wdT, unsigned short* __restrict__ ob,
    const int* __restrict__ offs) {
  __shared__ __align__(16) unsigned short As[4096], Bs[4096];
  int sb = blockIdx.y * 128;
  int n0 = blockIdx.x * 128;
  if (sb >= offs[8]) return;
  int e = 0;
  #pragma unroll
  for (int i = 1; i < 8; ++i) if (sb >= offs[i]) e = i;
  int tid = threadIdx.x, w = tid >> 6, l = tid & 63, lr = l & 15, lg = l >> 4;
  const unsigned short* ga0 = hb + (size_t)(sb + 32 * w + lr) * FDIM + lg * 8;
  const unsigned short* ga1 = ga0 + (size_t)16 * FDIM;
  const unsigned short* WdE = wdT + (size_t)e * 768 * FDIM;
  const unsigned short* gb0 = WdE + (size_t)(n0 + 32 * w + lr) * FDIM + lg * 8;
  const unsigned short* gb1 = gb0 + (size_t)16 * FDIM;
  f32x4 acc[4][4];
  #pragma unroll
  for (int i = 0; i < 4; ++i)
    #pragma unroll
    for (int j = 0; j < 4; ++j) acc[i][j] = (f32x4){0.f, 0.f, 0.f, 0.f};
  int wr = w >> 1, wc = w & 1;
  for (int k0 = 0; k0 < FDIM; k0 += 32) {
    gload16(ga0 + k0, As + 1024 * w);
    gload16(ga1 + k0, As + 1024 * w + 512);
    gload16(gb0 + k0, Bs + 1024 * w);
    gload16(gb1 + k0, Bs + 1024 * w + 512);
    __syncthreads();
    short8 af[4], bf[4];
    #pragma unroll
    for (int i = 0; i < 4; ++i) af[i] = *(const short8*)(As + (wr * 4 + i) * 512 + l * 8);
    #pragma unroll
    for (int j = 0; j < 4; ++j) bf[j] = *(const short8*)(Bs + (wc * 4 + j) * 512 + l * 8);
    #pragma unroll
    for (int i = 0; i < 4; ++i)
      #pragma unroll
      for (int j = 0; j < 4; ++j)
        acc[i][j] = __builtin_amdgcn_mfma_f32_16x16x32_bf16(af[i], bf[j], acc[i][j], 0, 0, 0);
    __syncthreads();
  }
  int colb = n0 + wc * 64 + lr;
  int rowb = sb + wr * 64 + lg * 4;
  #pragma unroll
  for (int i = 0; i < 4; ++i)
    #pragma unroll
    for (int j = 0; j < 4; ++j) {
      int col = colb + j * 16;
      #pragma unroll
      for (int r = 0; r < 4; ++r)
        ob[(size_t)(rowb + i * 16 + r) * 768 + col] = f2bf(acc[i][j][r]);
    }
}

// ---------------------------------------------------------------- attention (f32, register-tiled)
__global__ __launch_bounds__(256) void attn_k(const float* __restrict__ qkv,
                                              unsigned short* __restrict__ ax2, size_t pPS) {
  int pr = blockIdx.x, h = blockIdx.y, b = blockIdx.z;
  int tid = threadIdx.x;
  int ty4 = (tid >> 4) << 2, tx4 = (tid & 15) << 2;
  __shared__ float qs[64][68];    // [d][q]
  __shared__ float kps[64][68];   // [d][k] during QK, then [q][k] = P during PV
  __shared__ float vs[64][68];    // [k][d]
  int lr = tid >> 2;
  int lc = (tid & 3) << 4;
  for (int half = 0; half < 2; ++half) {
    int qt = half ? (15 - pr) : pr;
    int q0 = qt << 6;
    size_t qbase = ((size_t)(b * 1024 + q0 + lr)) * 2304 + h * 64 + lc;
    #pragma unroll
    for (int i = 0; i < 4; ++i) {
      float4 v = *(const float4*)(qkv + qbase + 4 * i);
      qs[lc + 4 * i + 0][lr] = v.x;
      qs[lc + 4 * i + 1][lr] = v.y;
      qs[lc + 4 * i + 2][lr] = v.z;
      qs[lc + 4 * i + 3][lr] = v.w;
    }
    float acc[4][4];
    float m[4], l[4];
    #pragma unroll
    for (int i = 0; i < 4; ++i) {
      m[i] = -3.0e38f; l[i] = 0.0f;
      #pragma unroll
      for (int j = 0; j < 4; ++j) acc[i][j] = 0.0f;
    }
    for (int kt = 0; kt <= qt; ++kt) {
      int k0 = kt << 6;
      __syncthreads();
      size_t kb = ((size_t)(b * 1024 + k0 + lr)) * 2304 + 768 + h * 64 + lc;
      #pragma unroll
      for (int i = 0; i < 4; ++i) {
        float4 kv = *(const float4*)(qkv + kb + 4 * i);
        kps[lc + 4 * i + 0][lr] = kv.x;
        kps[lc + 4 * i + 1][lr] = kv.y;
        kps[lc + 4 * i + 2][lr] = kv.z;
        kps[lc + 4 * i + 3][lr] = kv.w;
        *(float4*)&vs[lr][lc + 4 * i] = *(const float4*)(qkv + kb + 768 + 4 * i);
      }
      __syncthreads();
      float s[4][4];
      #pragma unroll
      for (int i = 0; i < 4; ++i)
        #pragma unroll
        for (int j = 0; j < 4; ++j) s[i][j] = 0.0f;
      #pragma unroll 8
      for (int d = 0; d < 64; ++d) {
        float4 qv = *(const float4*)&qs[d][ty4];
        float4 kv = *(const float4*)&kps[d][tx4];
        float qa[4] = {qv.x, qv.y, qv.z, qv.w};
        float ka[4] = {kv.x, kv.y, kv.z, kv.w};
        #pragma unroll
        for (int i = 0; i < 4; ++i)
          #pragma unroll
          for (int j = 0; j < 4; ++j) s[i][j] += qa[i] * ka[j];
      }
      bool diag = (kt == qt);
      #pragma unroll
      for (int i = 0; i < 4; ++i) {
        #pragma unroll
        for (int j = 0; j < 4; ++j) {
          if (diag && (tx4 + j > ty4 + i)) s[i][j] = -1.0e30f;
          else s[i][j] *= 0.125f;
        }
        float mx = fmaxf(fmaxf(s[i][0], s[i][1]), fmaxf(s[i][2], s[i][3]));
        mx = fmaxf(mx, __shfl_xor(mx, 1));
        mx = fmaxf(mx, __shfl_xor(mx, 2));
        mx = fmaxf(mx, __shfl_xor(mx, 4));
        mx = fmaxf(mx, __shfl_xor(mx, 8));
        float mnew = fmaxf(m[i], mx);
        float c = expf(m[i] - mnew);
        float rs = 0.0f;
        #pragma unroll
        for (int j = 0; j < 4; ++j) { s[i][j] = expf(s[i][j] - mnew); rs += s[i][j]; }
        rs += __shfl_xor(rs, 1);
        rs += __shfl_xor(rs, 2);
        rs += __shfl_xor(rs, 4);
        rs += __shfl_xor(rs, 8);
        l[i] = l[i] * c + rs;
        m[i] = mnew;
        #pragma unroll
        for (int j = 0; j < 4; ++j) acc[i][j] *= c;
      }
      __syncthreads();
      #pragma unroll
      for (int i = 0; i < 4; ++i)
        *(float4*)&kps[ty4 + i][tx4] = make_float4(s[i][0], s[i][1], s[i][2], s[i][3]);
      __syncthreads();
      #pragma unroll 4
      for (int kk = 0; kk < 16; ++kk) {
        float4 v0 = *(const float4*)&vs[(kk << 2) + 0][tx4];
        float4 v1 = *(const float4*)&vs[(kk << 2) + 1][tx4];
        float4 v2 = *(const float4*)&vs[(kk << 2) + 2][tx4];
        float4 v3 = *(const float4*)&vs[(kk << 2) + 3][tx4];
        #pragma unroll
        for (int i = 0; i < 4; ++i) {
          float4 p4 = *(const float4*)&kps[ty4 + i][kk << 2];
          acc[i][0] += p4.x * v0.x + p4.y * v1.x + p4.z * v2.x + p4.w * v3.x;
          acc[i][1] += p4.x * v0.y + p4.y * v1.y + p4.z * v2.y + p4.w * v3.y;
          acc[i][2] += p4.x * v0.z + p4.y * v1.z + p4.z * v2.z + p4.w * v3.z;
          acc[i][3] += p4.x * v0.w + p4.y * v1.w + p4.z * v2.w + p4.w * v3.w;
        }
      }
    }
    __syncthreads();
    #pragma unroll
    for (int i = 0; i < 4; ++i) {
      float invl = 1.0f / l[i];
      size_t ob = ((size_t)(b * 1024 + q0 + ty4 + i)) * 768 + h * 64 + tx4;
      ushort4 vh, vm;
      unsigned short a0, a1;
      split2f(acc[i][0] * invl, a0, a1); vh.x = a0; vm.x = a1;
      split2f(acc[i][1] * invl, a0, a1); vh.y = a0; vm.y = a1;
      split2f(acc[i][2] * invl, a0, a1); vh.z = a0; vm.z = a1;
      split2f(acc[i][3] * invl, a0, a1); vh.w = a0; vm.w = a1;
      *(ushort4*)(ax2 + ob) = vh;
      *(ushort4*)(ax2 + pPS + ob) = vm;
    }
  }
}

// ---------------------------------------------------------------- MoE routing (exact f32)
__global__ __launch_bounds__(256) void router_k(const float* __restrict__ xn,
                                                const float* __restrict__ rw,
                                                int* __restrict__ tk_idx, float* __restrict__ tk_w,
                                                int* __restrict__ cnt, float* __restrict__ psum) {
  __shared__ float bps[8];
  __shared__ int bcnt[8];
  int tid = threadIdx.x;
  if (tid < 8) { bps[tid] = 0.0f; bcnt[tid] = 0; }
  __syncthreads();
  int t = blockIdx.x * 4 + (tid >> 6);
  int lane = tid & 63;
  const float* xr = xn + (size_t)t * 768;
  float p[8] = {};
  for (int d = lane; d < 768; d += 64) {
    float xv = xr[d];
    const float* wr = rw + (size_t)d * 8;
    #pragma unroll
    for (int e = 0; e < 8; ++e) p[e] += xv * wr[e];
  }
  #pragma unroll
  for (int e = 0; e < 8; ++e) {
    float v = p[e];
    #pragma unroll
    for (int o = 32; o > 0; o >>= 1) v += __shfl_xor(v, o);
    p[e] = v;
  }
  if (lane == 0) {
    float mx = p[0];
    #pragma unroll
    for (int e = 1; e < 8; ++e) mx = fmaxf(mx, p[e]);
    float s = 0.0f;
    #pragma unroll
    for (int e = 0; e < 8; ++e) { p[e] = expf(p[e] - mx); s += p[e]; }
    float invs = 1.0f / s;
    #pragma unroll
    for (int e = 0; e < 8; ++e) p[e] *= invs;
    int i1 = 0; float v1 = p[0];
    #pragma unroll
    for (int e = 1; e < 8; ++e) if (p[e] > v1) { v1 = p[e]; i1 = e; }
    int i2 = (i1 == 0) ? 1 : 0; float v2 = p[i2];
    #pragma unroll
    for (int e = 0; e < 8; ++e) if (e != i1 && p[e] > v2) { v2 = p[e]; i2 = e; }
    float wsum = v1 + v2;
    tk_idx[t * 2] = i1; tk_idx[t * 2 + 1] = i2;
    tk_w[t * 2] = v1 / wsum; tk_w[t * 2 + 1] = v2 / wsum;
    atomicAdd(&bcnt[i1], 1); atomicAdd(&bcnt[i2], 1);
    #pragma unroll
    for (int e = 0; e < 8; ++e) atomicAdd(&bps[e], p[e]);
  }
  __syncthreads();
  if (tid < 8) {
    atomicAdd(&cnt[tid], bcnt[tid]);
    atomicAdd(&psum[tid], bps[tid]);
  }
}

__global__ void moe_offsets_k(const int* __restrict__ cnt, int* __restrict__ offs,
                              const float* __restrict__ psum, float* __restrict__ aux) {
  if (threadIdx.x == 0) {
    int o = 0; float a = 0.0f;
    for (int e = 0; e < 8; ++e) {
      offs[e] = o;
      o += (cnt[e] + 127) & ~127;
      a += ((float)cnt[e] / 4096.0f) * (psum[e] / 4096.0f);
    }
    offs[8] = o;
    aux[0] += a * 8.0f;
  }
}

__global__ void moe_fill_k(const int* __restrict__ tk_idx, const int* __restrict__ offs,
                           int* __restrict__ fill, int* __restrict__ slot_token,
                           int* __restrict__ tk_slot) {
  int i = blockIdx.x * 256 + threadIdx.x;              // grid 32
  int e = tk_idx[i];
  int pos = atomicAdd(&fill[e], 1);
  int slot = offs[e] + pos;
  slot_token[slot] = i >> 1;
  tk_slot[i] = slot;
}

template <int BF>  // 0: os f32; 1: os bf16
__global__ void moe_combine_k(float* __restrict__ x, const void* __restrict__ osv,
                              const int* __restrict__ tk_slot, const float* __restrict__ tk_w) {
  int t = blockIdx.x;                                  // grid 4096 x 192
  int d = threadIdx.x << 2;
  int s0 = tk_slot[t * 2], s1 = tk_slot[t * 2 + 1];
  float w0 = tk_w[t * 2], w1 = tk_w[t * 2 + 1];
  float a0, a1, a2, a3, b0, b1, b2, b3;
  if (BF == 0) {
    const float* os = (const float*)osv;
    float4 a = *(const float4*)(os + (size_t)s0 * 768 + d);
    float4 b = *(const float4*)(os + (size_t)s1 * 768 + d);
    a0 = a.x; a1 = a.y; a2 = a.z; a3 = a.w;
    b0 = b.x; b1 = b.y; b2 = b.z; b3 = b.w;
  } else {
    const unsigned short* os = (const unsigned short*)osv;
    ushort4 a = *(const ushort4*)(os + (size_t)s0 * 768 + d);
    ushort4 b = *(const ushort4*)(os + (size_t)s1 * 768 + d);
    a0 = bf2f(a.x); a1 = bf2f(a.y); a2 = bf2f(a.z); a3 = bf2f(a.w);
    b0 = bf2f(b.x); b1 = bf2f(b.y); b2 = bf2f(b.z); b3 = bf2f(b.w);
  }
  float4 c = *(const float4*)(x + (size_t)t * 768 + d);
  c.x += w0 * a0 + w1 * b0;
  c.y += w0 * a1 + w1 * b1;
  c.z += w0 * a2 + w1 * b2;
  c.w += w0 * a3 + w1 * b3;
  *(float4*)(x + (size_t)t * 768 + d) = c;
}

__global__ void write_aux_k(const float* __restrict__ aux, float* __restrict__ out) {
  out[0] = aux[0];
}

// ---------------------------------------------------------------- host launcher

extern "C" void kernel_launch(void* const* d_in, const int* in_sizes, int n_in,
                              void* d_out, int out_size, void* d_ws, size_t ws_size,
                              hipStream_t stream) {
  const int* input_ids      = (const int*)d_in[0];
  const int* time_slots     = (const int*)d_in[1];
  const int* day_of_week    = (const int*)d_in[2];
  const int* month          = (const int*)d_in[3];
  const int* is_holiday     = (const int*)d_in[4];
  const int* location_ids   = (const int*)d_in[5];
  const int* road_types     = (const int*)d_in[6];
  const int* weather_states = (const int*)d_in[7];
  const float* word_emb     = (const float*)d_in[8];
  const float* time_emb     = (const float*)d_in[9];
  const float* dow_emb      = (const float*)d_in[10];
  const float* month_emb    = (const float*)d_in[11];
  const float* hol_emb      = (const float*)d_in[12];
  const float* loc_emb      = (const float*)d_in[13];
  const float* road_emb     = (const float*)d_in[14];
  const float* weather_emb  = (const float*)d_in[15];
  const float* proj_w       = (const float*)d_in[16];
  const float* proj_b       = (const float*)d_in[17];
  const float* emb_norm_w   = (const float*)d_in[18];
  const float* norm1_w      = (const float*)d_in[19];
  const float* Wq           = (const float*)d_in[20];
  const float* Wk           = (const float*)d_in[21];
  const float* Wv           = (const float*)d_in[22];
  const float* Wo           = (const float*)d_in[23];
  const float* norm2_w      = (const float*)d_in[24];
  const float* router_w     = (const float*)d_in[25];
  const float* Wg           = (const float*)d_in[26];
  const float* Wu           = (const float*)d_in[27];
  const float* Wd           = (const float*)d_in[28];
  const float* final_norm_w = (const float*)d_in[29];
  float* out = (float*)d_out;

  const size_t TD = (size_t)TTOK * 768;
  const size_t REG = (size_t)MAXSLOT * FDIM * 4;       // 113.25 MB shared regions
  const size_t HPS = (size_t)MAXSLOT * FDIM;           // h plane stride (elements)
  char* base = (char*)d_ws;
  auto carve = [&](size_t bytes) { char* p = base; base += (bytes + 255) & ~(size_t)255; return p; };
  float* x    = (float*)carve(TD * 4);
  float* xn   = (float*)carve(TD * 4);
  float* cosb = (float*)carve(32768 * 4);
  float* sinb = (float*)carve(32768 * 4);
  float* ctx  = (float*)carve(4 * 1536 * 4);
  float* biasB= (float*)carve(4 * 768 * 4);
  float* tkw  = (float*)carve(8192 * 4);
  float* psum = (float*)carve(64);
  float* auxa = (float*)carve(64);
  int* cnt    = (int*)carve(64);
  int* fill   = (int*)carve(64);
  int* offs   = (int*)carve(64);
  int* tk_idx = (int*)carve(8192 * 4);
  int* tk_slot= (int*)carve(8192 * 4);
  int* slot_token = (int*)carve(MAXSLOT * 4);
  unsigned short* zp = (unsigned short*)carve(4096);
  unsigned short* xnb3 = (unsigned short*)carve(3 * TD * 2);
  char* QAH = carve(REG);                               // qkv+ax2 (attn) / h planes (moe)
  char* GT  = carve(REG);                               // gtmp / g|u halves / ob
  char* Wr  = carve(REG);                               // weight planes (sequential)
  float* qkv = (float*)QAH;
  unsigned short* ax2 = (unsigned short*)(QAH + (size_t)TTOK * 2304 * 4);
  unsigned short* hpl = (unsigned short*)QAH;           // L0: h split-2 planes (2*HPS ushort)
  unsigned short* hb16 = (unsigned short*)QAH;          // L1: h bf16
  float* gtmp = (float*)GT;
  float* obf = (float*)GT;
  unsigned short* gu16 = (unsigned short*)GT;           // L1: g at [0], u at +HPS
  unsigned short* ob16 = (unsigned short*)GT;
  unsigned short* wpl = (unsigned short*)Wr;

  const size_t PS_D = (size_t)768 * 768;
  const size_t PS_QKV = (size_t)2304 * 768;
  const size_t PS_E = (size_t)8 * FDIM * 768;

  hipMemsetAsync(auxa, 0, 64, stream);
  hipMemsetAsync(zp, 0, 4096, stream);
  rope_cache_k<<<dim3(1024), dim3(32), 0, stream>>>(cosb, sinb);
  build_ctx_k<<<dim3(4, 6), dim3(256), 0, stream>>>(time_slots, day_of_week, month, is_holiday,
      location_ids, road_types, weather_states, time_emb, dow_emb, month_emb, hol_emb,
      loc_emb, road_emb, weather_emb, ctx);
  build_bias_k<<<dim3(4, 3), dim3(256), 0, stream>>>(ctx, proj_w, proj_b, biasB);
  tconv3_k<<<dim3(12, 12, 1), dim3(64, 4), 0, stream>>>(proj_w, wpl, PS_D, 768, 768, 0, 0);
  gconv3_k<<<dim3(TTOK), dim3(192), 0, stream>>>(word_emb, input_ids, xnb3, TD);
  gemm3<3><<<dim3(6, 32), dim3(256), 0, stream>>>(xnb3, TD, wpl, PS_D, xn, 768, 768, biasB);
  rmsnorm_k<0><<<dim3(TTOK), dim3(256), 0, stream>>>(xn, emb_norm_w, x, nullptr, 0);

  for (int l = 0; l < 2; ++l) {
    const float* rw = router_w + (size_t)l * 768 * 8;
    // ---- attention (split-2 GEMMs, f32 flash core) ----
    tconv2_k<<<dim3(12, 12, 1), dim3(64, 4), 0, stream>>>(Wq + (size_t)l * PS_D, wpl, PS_QKV, 768, 768, 0, 0);
    tconv2_k<<<dim3(12, 12, 1), dim3(64, 4), 0, stream>>>(Wk + (size_t)l * PS_D, wpl + PS_D, PS_QKV, 768, 768, 0, 0);
    tconv2_k<<<dim3(12, 12, 1), dim3(64, 4), 0, stream>>>(Wv + (size_t)l * PS_D, wpl + 2 * PS_D, PS_QKV, 768, 768, 0, 0);
    rmsnorm_k<1><<<dim3(TTOK), dim3(256), 0, stream>>>(x, norm1_w + l * 768, nullptr, xnb3, TD);
    gemm2<0><<<dim3(18, 32), dim3(256), 0, stream>>>(xnb3, TD, wpl, PS_QKV, qkv, 2304, 768);
    rope_apply_k<<<dim3(6144), dim3(256), 0, stream>>>(qkv, cosb, sinb);
    attn_k<<<dim3(8, 12, 4), dim3(256), 0, stream>>>(qkv, ax2, TD);
    tconv2_k<<<dim3(12, 12, 1), dim3(64, 4), 0, stream>>>(Wo + (size_t)l * PS_D, wpl, PS_D, 768, 768, 0, 0);
    gemm2<2><<<dim3(6, 32), dim3(256), 0, stream>>>(ax2, TD, wpl, PS_D, x, 768, 768);

    // ---- MoE ----
    if (l == 0)
      rmsnorm_k<2><<<dim3(TTOK), dim3(256), 0, stream>>>(x, norm2_w, xn, xnb3, TD);
    else
      rmsnorm_k<3><<<dim3(TTOK), dim3(256), 0, stream>>>(x, norm2_w + 768, xn, xnb3, TD);
    hipMemsetAsync(cnt, 0, 64, stream);
    hipMemsetAsync(fill, 0, 64, stream);
    hipMemsetAsync(psum, 0, 64, stream);
    hipMemsetAsync(slot_token, 0xFF, MAXSLOT * 4, stream);
    router_k<<<dim3(1024), dim3(256), 0, stream>>>(xn, rw, tk_idx, tkw, cnt, psum);
    moe_offsets_k<<<dim3(1), dim3(64), 0, stream>>>(cnt, offs, psum, auxa);
    moe_fill_k<<<dim3(32), dim3(256), 0, stream>>>(tk_idx, offs, fill, slot_token, tk_slot);
    if (l == 0) {
      // split-2 experts; 2D grids (n fastest -> implicit XCD alignment)
      tconv2_k<<<dim3(48, 12, 8), dim3(64, 4), 0, stream>>>(Wg, wpl, PS_E,
          768, FDIM, (size_t)768 * FDIM, (size_t)FDIM * 768);
      gemm2_gu<0><<<dim3(24, 72), dim3(256), 0, stream>>>(xnb3, TD, wpl, PS_E,
          gtmp, nullptr, 0, nullptr, slot_token, offs, zp);
      tconv2_k<<<dim3(48, 12, 8), dim3(64, 4), 0, stream>>>(Wu, wpl, PS_E,
          768, FDIM, (size_t)768 * FDIM, (size_t)FDIM * 768);
      gemm2_gu<1><<<dim3(24, 72), dim3(256), 0, stream>>>(xnb3, TD, wpl, PS_E,
          nullptr, hpl, HPS, gtmp, slot_token, offs, zp);
      tconv2_k<<<dim3(12, 48, 8), dim3(64, 4), 0, stream>>>(Wd, wpl, PS_E,
          FDIM, 768, (size_t)FDIM * 768, (size_t)768 * FDIM);
      gemm2_dn<<<dim3(6, 72), dim3(256), 0, stream>>>(hpl, HPS, wpl, PS_E, obf, offs);
      moe_combine_k<0><<<dim3(TTOK), dim3(192), 0, stream>>>(x, obf, tk_slot, tkw);
    } else {
      // plain bf16 experts; 2D grids
      const float* wg1 = Wg + (size_t)8 * 768 * FDIM;
      const float* wu1 = Wu + (size_t)8 * 768 * FDIM;
      const float* wd1 = Wd + (size_t)8 * FDIM * 768;
      tconv_k<<<dim3(48, 12, 8), dim3(64, 4), 0, stream>>>(wg1, wpl,
          768, FDIM, (size_t)768 * FDIM, (size_t)FDIM * 768);
      tconv_k<<<dim3(48, 12, 8), dim3(64, 4), 0, stream>>>(wu1, wpl + PS_E,
          768, FDIM, (size_t)768 * FDIM, (size_t)FDIM * 768);
      gemm_gu2<<<dim3(48, 72), dim3(256), 0, stream>>>(xnb3, wpl, wpl + PS_E,
          gu16, slot_token, offs, zp);
      silu_mul_k<<<dim3((int)((size_t)MAXSLOT * FDIM / 2048)), dim3(256), 0, stream>>>(gu16, hb16);
      tconv_k<<<dim3(12, 48, 8), dim3(64, 4), 0, stream>>>(wd1, wpl,
          FDIM, 768, (size_t)FDIM * 768, (size_t)768 * FDIM);
      gemm_d<<<dim3(6, 72), dim3(256), 0, stream>>>(hb16, wpl, ob16, offs);
      moe_combine_k<1><<<dim3(TTOK), dim3(192), 0, stream>>>(x, ob16, tk_slot, tkw);
    }
  }

  rmsnorm_k<0><<<dim3(TTOK), dim3(256), 0, stream>>>(x, final_norm_w, out, nullptr, 0);
  write_aux_k<<<dim3(1), dim3(1), 0, stream>>>(auxa, out + TD);
}